// Round 1
// baseline (370.405 us; speedup 1.0000x reference)
//
// MemFullAttention_19585050870313 — MI355X round 1
// Pipeline:
//   gather+cast x->bf16 (only needed rows)      ~190MB traffic
//   QKV GEMMs  (bf16 MFMA, m97-style 128x128)   23.6 + 103.1 GF
//   V transpose (per b,chunk,head -> [d][kv])   ~100MB
//   flash attention (MFMA 16x16x32, online SM)  ~35 GF
//   out GEMM (+bias, fp32 epilogue)             23.6 GF
#include <hip/hip_runtime.h>
#include <hip/hip_bf16.h>

typedef __bf16 bf16;
typedef __bf16 bf16x8 __attribute__((ext_vector_type(8)));
typedef float  f32x4  __attribute__((ext_vector_type(4)));
typedef float  f32x4v __attribute__((ext_vector_type(4)));
typedef unsigned int u32x4 __attribute__((ext_vector_type(4)));

#define DEV __device__ __forceinline__

DEV void gload_lds16(const bf16* g, bf16* l) {
    // 16B-wide global->LDS DMA; LDS dest = wave-uniform base + lane*16 (pass base of wave segment)
    __builtin_amdgcn_global_load_lds(
        (__attribute__((address_space(1))) void*)g,
        (__attribute__((address_space(3))) void*)l, 16, 0, 0);
}

DEV bf16x8 as_bf(u32x4 v) { return __builtin_bit_cast(bf16x8, v); }

DEV f32x4 mfma16(bf16x8 a, bf16x8 b, f32x4 c) {
    return __builtin_amdgcn_mfma_f32_16x16x32_bf16(a, b, c, 0, 0, 0);
}

// ---- problem constants (reference_length fixed at 3) ----
constexpr int D_   = 1024;      // model dim = heads*head_dim
constexpr int S_   = 256;       // H*W
constexpr int TOUT = 11;        // 7 pre-chunks + 4 frames of last chunk
constexpr int MQ   = 4 * TOUT * S_;   // 11264 query rows
constexpr int MKV  = 4 * 8 * 3 * S_;  // 24576 kv rows
constexpr int KVL  = 768;             // kv length per (b,chunk)

// ======================= gather + cast kernels =======================
// Aq row (b, t_out, s): q source time = t_out<7 ? 4*t_out : 28+(t_out-7)
__global__ void gather_q(const float* __restrict__ x, bf16* __restrict__ Aq) {
    const int idx  = blockIdx.x * 256 + threadIdx.x;   // grid exact: MQ*128 threads
    const int row  = idx >> 7, part = idx & 127;
    const int b    = row / (TOUT * S_);
    const int r2   = row - b * (TOUT * S_);
    const int tout = r2 >> 8;
    const int s    = r2 & 255;
    const int tx   = tout < 7 ? tout * 4 : 28 + (tout - 7);
    const float* src = x + ((size_t)((b * 32 + tx) * S_ + s)) * D_ + part * 8;
    f32x4v v0 = *(const f32x4v*)src;
    f32x4v v1 = *(const f32x4v*)(src + 4);
    bf16x8 o;
    o[0]=(bf16)v0[0]; o[1]=(bf16)v0[1]; o[2]=(bf16)v0[2]; o[3]=(bf16)v0[3];
    o[4]=(bf16)v1[0]; o[5]=(bf16)v1[1]; o[6]=(bf16)v1[2]; o[7]=(bf16)v1[3];
    *(bf16x8*)(Aq + (size_t)row * D_ + part * 8) = o;
}

// Akv row (b, chunk, j): frame = 1 + j/256, s = j%256
__global__ void gather_kv(const float* __restrict__ x, bf16* __restrict__ Akv) {
    const int idx = blockIdx.x * 256 + threadIdx.x;    // grid exact: MKV*128 threads
    const int row = idx >> 7, part = idx & 127;
    const int b   = row / 6144;
    const int r2  = row - b * 6144;
    const int c   = r2 / KVL;
    const int j   = r2 - c * KVL;
    const int f   = 1 + (j >> 8);
    const int s   = j & 255;
    const int tx  = c * 4 + f;
    const float* src = x + ((size_t)((b * 32 + tx) * S_ + s)) * D_ + part * 8;
    f32x4v v0 = *(const f32x4v*)src;
    f32x4v v1 = *(const f32x4v*)(src + 4);
    bf16x8 o;
    o[0]=(bf16)v0[0]; o[1]=(bf16)v0[1]; o[2]=(bf16)v0[2]; o[3]=(bf16)v0[3];
    o[4]=(bf16)v1[0]; o[5]=(bf16)v1[1]; o[6]=(bf16)v1[2]; o[7]=(bf16)v1[3];
    *(bf16x8*)(Akv + (size_t)row * D_ + part * 8) = o;
}

// ======================= weight transpose (f32 W[K=1024][N] -> bf16 Wt[N][1024]) ===
__global__ void wtrans(const float* __restrict__ W, bf16* __restrict__ Wt, int N) {
    __shared__ float T[64][65];
    const int bid = blockIdx.x;
    const int kt = bid & 15, nt = bid >> 4;     // K=1024 fixed -> 16 k-tiles
    const int k0 = kt * 64, n0 = nt * 64;
    for (int i = 0; i < 16; ++i) {
        const int e = i * 256 + (int)threadIdx.x;
        const int kk = e >> 6, nn = e & 63;
        T[nn][kk] = W[(size_t)(k0 + kk) * N + n0 + nn];
    }
    __syncthreads();
    for (int i = 0; i < 16; ++i) {
        const int e = i * 256 + (int)threadIdx.x;
        const int n = e >> 6, kk = e & 63;
        Wt[(size_t)(n0 + n) * 1024 + k0 + kk] = (bf16)T[n][kk];
    }
}

// ======================= V transpose: KV v-part -> Vt[(bg*16+h)][64 d][768 kv] ====
__global__ void vtrans(const bf16* __restrict__ KV, bf16* __restrict__ Vt) {
    __shared__ bf16 T[64][66];
    const int bid = blockIdx.x;
    const int jt = bid % 12;
    const int h  = (bid / 12) & 15;
    const int bg = bid / 192;
    const int j0 = jt * 64;
    const bf16* src = KV + (size_t)bg * KVL * 2048 + 1024 + h * 64;
    for (int i = 0; i < 16; ++i) {
        const int e = i * 256 + (int)threadIdx.x;
        const int j = e >> 6, dd = e & 63;
        T[dd][j] = src[(size_t)(j0 + j) * 2048 + dd];
    }
    __syncthreads();
    bf16* dst = Vt + ((size_t)(bg * 16 + h)) * 64 * KVL;
    for (int i = 0; i < 16; ++i) {
        const int e = i * 256 + (int)threadIdx.x;
        const int d = e >> 6, jj = e & 63;
        dst[(size_t)d * KVL + j0 + jj] = T[d][jj];
    }
}

// ======================= GEMM: C[M][N] = A[M][K] * Bt[N][K]^T =====================
// m97 structure: 128x128 tile, BK=32, 4 waves (2x2 of 64x64), global_load_lds w=16,
// 2 barriers/K-step. EPI=0: bf16 store. EPI=1: fp32 store + bias.
template<int EPI>
__global__ __launch_bounds__(256, 3) void gemm_bt(
    const bf16* __restrict__ A, const bf16* __restrict__ Bt,
    bf16* __restrict__ Cb, float* __restrict__ Cf,
    const float* __restrict__ bias, int M, int N, int K)
{
    __shared__ bf16 As[4096];   // [128 rows][32 k]
    __shared__ bf16 Bs[4096];   // [128 cols][32 k]
    const int tid = threadIdx.x, lane = tid & 63, wid = tid >> 6;
    const int mtiles = M >> 7;
    const int bm = blockIdx.x % mtiles;
    const int bn = blockIdx.x / mtiles;
    const int wr = wid >> 1, wc = wid & 1;
    const int l15 = lane & 15, l4 = lane >> 4;

    // staging: chunk = c*256 + wid*64 + lane -> row=chunk>>2, col8=chunk&3
    const int ii = wid * 64 + lane;
    const int r0 = ii >> 2, c0 = ii & 3;
    const bf16* ga0 = A  + (size_t)(bm * 128 + r0)      * K + c0 * 8;
    const bf16* ga1 = A  + (size_t)(bm * 128 + r0 + 64) * K + c0 * 8;
    const bf16* gb0 = Bt + (size_t)(bn * 128 + r0)      * K + c0 * 8;
    const bf16* gb1 = Bt + (size_t)(bn * 128 + r0 + 64) * K + c0 * 8;
    bf16* la0 = As + wid * 512;          // wave-uniform LDS bases
    bf16* la1 = As + 2048 + wid * 512;
    bf16* lb0 = Bs + wid * 512;
    bf16* lb1 = Bs + 2048 + wid * 512;

    const bf16* ra = As + (wr * 64 + l15) * 32 + l4 * 8;
    const bf16* rb = Bs + (wc * 64 + l15) * 32 + l4 * 8;

    f32x4 acc[4][4];
    const f32x4 zf = {0.f, 0.f, 0.f, 0.f};
    #pragma unroll
    for (int m = 0; m < 4; ++m)
        #pragma unroll
        for (int n = 0; n < 4; ++n) acc[m][n] = zf;

    for (int k0 = 0; k0 < K; k0 += 32) {
        gload_lds16(ga0, la0);
        gload_lds16(ga1, la1);
        gload_lds16(gb0, lb0);
        gload_lds16(gb1, lb1);
        ga0 += 32; ga1 += 32; gb0 += 32; gb1 += 32;
        __syncthreads();                 // drains vmcnt: tiles ready
        u32x4 af[4], bfr[4];
        #pragma unroll
        for (int m = 0; m < 4; ++m) af[m]  = *(const u32x4*)(ra + m * 512);
        #pragma unroll
        for (int n = 0; n < 4; ++n) bfr[n] = *(const u32x4*)(rb + n * 512);
        #pragma unroll
        for (int m = 0; m < 4; ++m)
            #pragma unroll
            for (int n = 0; n < 4; ++n)
                acc[m][n] = mfma16(as_bf(af[m]), as_bf(bfr[n]), acc[m][n]);
        __syncthreads();                 // all reads done before next stage
    }

    // epilogue: D layout col=lane&15, row=(lane>>4)*4+reg  [m89-verified]
    #pragma unroll
    for (int m = 0; m < 4; ++m) {
        const int row = bm * 128 + wr * 64 + m * 16 + l4 * 4;
        #pragma unroll
        for (int n = 0; n < 4; ++n) {
            const int col = bn * 128 + wc * 64 + n * 16 + l15;
            f32x4 v = acc[m][n];
            if (EPI == 0) {
                #pragma unroll
                for (int r = 0; r < 4; ++r)
                    Cb[(size_t)(row + r) * N + col] = (bf16)v[r];
            } else {
                const float bs = bias[col];
                #pragma unroll
                for (int r = 0; r < 4; ++r)
                    Cf[(size_t)(row + r) * N + col] = v[r] + bs;
            }
        }
    }
}

// ======================= flash attention ==========================================
// block = (b, chunk, qtile64, head); 4 waves x 16 q-rows; kv in 12 tiles of 64.
// Q in regs; K LDS [dhalf][key][32]; V LDS [khalf][d][32]; P via padded per-wave LDS.
__global__ __launch_bounds__(256, 3) void attn_fwd(
    const bf16* __restrict__ Q, const bf16* __restrict__ KV,
    const bf16* __restrict__ Vt, bf16* __restrict__ O)
{
    __shared__ bf16 Kl[2][64][32];
    __shared__ bf16 Vl[2][64][32];
    __shared__ bf16 Pl[4][16][88];   // stride 176B: 16B-aligned, 2-way banks only

    const int tid = threadIdx.x, lane = tid & 63, wid = tid >> 6;
    int bid = blockIdx.x;
    const int h = bid & 15; bid >>= 4;
    const int qt = bid % 44, b = bid / 44;
    const int chunk = qt < 28 ? (qt >> 2) : 7;
    const int qrow0 = b * (TOUT * S_) +
                      (qt < 28 ? chunk * S_ + (qt & 3) * 64 : 7 * S_ + (qt - 28) * 64);

    const bf16* kg = KV + ((size_t)(b * 8 + chunk) * KVL) * 2048 + h * 64;
    const bf16* vg = Vt + ((size_t)((b * 8 + chunk) * 16 + h)) * 64 * KVL;

    const int l15 = lane & 15, l4 = lane >> 4;

    // Q fragments (A operand): lane holds Q[row=l&15][8*(l>>4)+j]
    const int qrow = qrow0 + wid * 16 + l15;
    const bf16* qp = Q + (size_t)qrow * D_ + h * 64 + l4 * 8;
    const u32x4 q0 = *(const u32x4*)qp;
    const u32x4 q1 = *(const u32x4*)(qp + 32);

    float m_r[4], l_r[4], al[4];
    f32x4 oacc[4];
    const f32x4 zf = {0.f, 0.f, 0.f, 0.f};
    #pragma unroll
    for (int r = 0; r < 4; ++r) { m_r[r] = -1e30f; l_r[r] = 0.f; }
    #pragma unroll
    for (int n = 0; n < 4; ++n) oacc[n] = zf;

    const int ii = wid * 64 + lane;
    const int srow = ii >> 2, sc = ii & 3;
    bf16* kld = &Kl[0][0][0] + wid * 512;
    bf16* vld = &Vl[0][0][0] + wid * 512;
    const float scale = 0.125f;   // 1/sqrt(64)

    for (int kt = 0; kt < 12; ++kt) {
        const int kv0 = kt * 64;
        __syncthreads();   // previous tile fully consumed
        gload_lds16(kg + (size_t)(kv0 + srow) * 2048 + sc * 8,      kld);
        gload_lds16(kg + (size_t)(kv0 + srow) * 2048 + 32 + sc * 8, kld + 2048);
        gload_lds16(vg + (size_t)srow * KVL + kv0 + sc * 8,         vld);
        gload_lds16(vg + (size_t)srow * KVL + kv0 + 32 + sc * 8,    vld + 2048);
        __syncthreads();   // tiles ready (vmcnt drained)

        // S = Q K^T: 16 q-rows x 64 keys per wave
        f32x4 s[4];
        #pragma unroll
        for (int n = 0; n < 4; ++n) {
            const bf16* kp = &Kl[0][n * 16 + l15][l4 * 8];
            const u32x4 b0 = *(const u32x4*)kp;
            const u32x4 b1 = *(const u32x4*)(kp + 2048);
            f32x4 t = mfma16(as_bf(q0), as_bf(b0), zf);
            s[n] = mfma16(as_bf(q1), as_bf(b1), t);
        }

        // online softmax; S frag: row=(l>>4)*4+r, col=key=n*16+(l&15)
        #pragma unroll
        for (int r = 0; r < 4; ++r) {
            float v = fmaxf(fmaxf(s[0][r], s[1][r]), fmaxf(s[2][r], s[3][r]));
            #pragma unroll
            for (int off = 1; off <= 8; off <<= 1)
                v = fmaxf(v, __shfl_xor(v, off));
            const float mn = fmaxf(m_r[r], v * scale);
            al[r] = __expf(m_r[r] - mn);
            m_r[r] = mn;
            const float p0 = __expf(s[0][r] * scale - mn);
            const float p1 = __expf(s[1][r] * scale - mn);
            const float p2 = __expf(s[2][r] * scale - mn);
            const float p3 = __expf(s[3][r] * scale - mn);
            float sum = p0 + p1 + p2 + p3;
            #pragma unroll
            for (int off = 1; off <= 8; off <<= 1)
                sum += __shfl_xor(sum, off);
            l_r[r] = l_r[r] * al[r] + sum;
            Pl[wid][l4 * 4 + r][l15]      = (bf16)p0;
            Pl[wid][l4 * 4 + r][16 + l15] = (bf16)p1;
            Pl[wid][l4 * 4 + r][32 + l15] = (bf16)p2;
            Pl[wid][l4 * 4 + r][48 + l15] = (bf16)p3;
        }
        #pragma unroll
        for (int n = 0; n < 4; ++n)
            #pragma unroll
            for (int r = 0; r < 4; ++r) oacc[n][r] *= al[r];

        // cross-lane LDS hazard: drain DS ops before reading other lanes' P
        asm volatile("s_waitcnt lgkmcnt(0)" ::: "memory");

        // O += P V
        #pragma unroll
        for (int kk = 0; kk < 2; ++kk) {
            const u32x4 pa = *(const u32x4*)(&Pl[wid][l15][kk * 32 + l4 * 8]);
            #pragma unroll
            for (int n = 0; n < 4; ++n) {
                const u32x4 bv = *(const u32x4*)(&Vl[kk][n * 16 + l15][l4 * 8]);
                oacc[n] = mfma16(as_bf(pa), as_bf(bv), oacc[n]);
            }
        }
    }

    #pragma unroll
    for (int r = 0; r < 4; ++r) {
        const float inv = 1.f / l_r[r];
        const size_t row = (size_t)(qrow0 + wid * 16 + l4 * 4 + r) * D_;
        #pragma unroll
        for (int n = 0; n < 4; ++n)
            O[row + h * 64 + n * 16 + l15] = (bf16)(oacc[n][r] * inv);
    }
}

// ======================= launch ====================================================
extern "C" void kernel_launch(void* const* d_in, const int* in_sizes, int n_in,
                              void* d_out, int out_size, void* d_ws, size_t ws_size,
                              hipStream_t stream) {
    (void)in_sizes; (void)n_in; (void)out_size; (void)ws_size;
    const float* x    = (const float*)d_in[0];
    const float* Wqkv = (const float*)d_in[1];
    const float* Wout = (const float*)d_in[2];
    const float* bout = (const float*)d_in[3];

    // workspace layout (bf16 elems); ~196MB with aliasing
    bf16* Aq     = (bf16*)d_ws;                       // 11264*1024
    bf16* Akv    = Aq     + (size_t)MQ  * 1024;       // 24576*1024
    bf16* Wqkv_t = Akv    + (size_t)MKV * 1024;       // 3072*1024   [N][K]
    bf16* Wout_t = Wqkv_t + (size_t)3072 * 1024;      // 1024*1024
    bf16* Qb     = Wout_t + (size_t)1024 * 1024;      // 11264*1024
    bf16* KVb    = Qb     + (size_t)MQ  * 1024;       // 24576*2048 (k | v)
    bf16* Vtb    = Akv;   // alias: Akv dead after GEMM2
    bf16* Ob     = Aq;    // alias: Aq dead after GEMM1

    gather_q <<<MQ  * 128 / 256, 256, 0, stream>>>(x, Aq);
    gather_kv<<<MKV * 128 / 256, 256, 0, stream>>>(x, Akv);
    wtrans<<<16 * 48, 256, 0, stream>>>(Wqkv, Wqkv_t, 3072);
    wtrans<<<16 * 16, 256, 0, stream>>>(Wout, Wout_t, 1024);

    gemm_bt<0><<<(MQ / 128) * (1024 / 128), 256, 0, stream>>>(
        Aq, Wqkv_t, Qb, nullptr, nullptr, MQ, 1024, 1024);
    gemm_bt<0><<<(MKV / 128) * (2048 / 128), 256, 0, stream>>>(
        Akv, Wqkv_t + (size_t)1024 * 1024, KVb, nullptr, nullptr, MKV, 2048, 1024);

    vtrans<<<32 * 16 * 12, 256, 0, stream>>>(KVb, Vtb);
    attn_fwd<<<4 * 44 * 16, 256, 0, stream>>>(Qb, KVb, Vtb, Ob);

    gemm_bt<1><<<(MQ / 128) * (1024 / 128), 256, 0, stream>>>(
        Ob, Wout_t, nullptr, (float*)d_out, bout, MQ, 1024, 1024);
}

// Round 2
// 352.382 us; speedup vs baseline: 1.0511x; 1.0511x over previous
//
// MemFullAttention_19585050870313 — MI355X round 2
// Change: replace m97-style 128x128 GEMM with the 256x256 8-phase template
// (T2 LDS XOR-swizzle + T3/T4 counted-vmcnt pipeline + T5 setprio + T1 XCD swizzle).
// Attn / gathers / transposes unchanged from round 1.
#include <hip/hip_runtime.h>
#include <hip/hip_bf16.h>

typedef __bf16 bf16;
typedef __bf16 bf16x8 __attribute__((ext_vector_type(8)));
typedef float  f32x4  __attribute__((ext_vector_type(4)));
typedef float  f32x4v __attribute__((ext_vector_type(4)));
typedef unsigned int u32x4 __attribute__((ext_vector_type(4)));

#define DEV __device__ __forceinline__

DEV void gload_lds16(const bf16* g, bf16* l) {
    __builtin_amdgcn_global_load_lds(
        (__attribute__((address_space(1))) void*)g,
        (__attribute__((address_space(3))) void*)l, 16, 0, 0);
}

DEV bf16x8 as_bf(u32x4 v) { return __builtin_bit_cast(bf16x8, v); }

DEV f32x4 mfma16(bf16x8 a, bf16x8 b, f32x4 c) {
    return __builtin_amdgcn_mfma_f32_16x16x32_bf16(a, b, c, 0, 0, 0);
}

// ---- problem constants (reference_length fixed at 3) ----
constexpr int D_   = 1024;
constexpr int S_   = 256;
constexpr int TOUT = 11;
constexpr int MQ   = 4 * TOUT * S_;   // 11264
constexpr int MKV  = 4 * 8 * 3 * S_;  // 24576
constexpr int KVL  = 768;

// ======================= gather + cast kernels =======================
__global__ void gather_q(const float* __restrict__ x, bf16* __restrict__ Aq) {
    const int idx  = blockIdx.x * 256 + threadIdx.x;
    const int row  = idx >> 7, part = idx & 127;
    const int b    = row / (TOUT * S_);
    const int r2   = row - b * (TOUT * S_);
    const int tout = r2 >> 8;
    const int s    = r2 & 255;
    const int tx   = tout < 7 ? tout * 4 : 28 + (tout - 7);
    const float* src = x + ((size_t)((b * 32 + tx) * S_ + s)) * D_ + part * 8;
    f32x4v v0 = *(const f32x4v*)src;
    f32x4v v1 = *(const f32x4v*)(src + 4);
    bf16x8 o;
    o[0]=(bf16)v0[0]; o[1]=(bf16)v0[1]; o[2]=(bf16)v0[2]; o[3]=(bf16)v0[3];
    o[4]=(bf16)v1[0]; o[5]=(bf16)v1[1]; o[6]=(bf16)v1[2]; o[7]=(bf16)v1[3];
    *(bf16x8*)(Aq + (size_t)row * D_ + part * 8) = o;
}

__global__ void gather_kv(const float* __restrict__ x, bf16* __restrict__ Akv) {
    const int idx = blockIdx.x * 256 + threadIdx.x;
    const int row = idx >> 7, part = idx & 127;
    const int b   = row / 6144;
    const int r2  = row - b * 6144;
    const int c   = r2 / KVL;
    const int j   = r2 - c * KVL;
    const int f   = 1 + (j >> 8);
    const int s   = j & 255;
    const int tx  = c * 4 + f;
    const float* src = x + ((size_t)((b * 32 + tx) * S_ + s)) * D_ + part * 8;
    f32x4v v0 = *(const f32x4v*)src;
    f32x4v v1 = *(const f32x4v*)(src + 4);
    bf16x8 o;
    o[0]=(bf16)v0[0]; o[1]=(bf16)v0[1]; o[2]=(bf16)v0[2]; o[3]=(bf16)v0[3];
    o[4]=(bf16)v1[0]; o[5]=(bf16)v1[1]; o[6]=(bf16)v1[2]; o[7]=(bf16)v1[3];
    *(bf16x8*)(Akv + (size_t)row * D_ + part * 8) = o;
}

// ======================= weight transpose ===========================
__global__ void wtrans(const float* __restrict__ W, bf16* __restrict__ Wt, int N) {
    __shared__ float T[64][65];
    const int bid = blockIdx.x;
    const int kt = bid & 15, nt = bid >> 4;
    const int k0 = kt * 64, n0 = nt * 64;
    for (int i = 0; i < 16; ++i) {
        const int e = i * 256 + (int)threadIdx.x;
        const int kk = e >> 6, nn = e & 63;
        T[nn][kk] = W[(size_t)(k0 + kk) * N + n0 + nn];
    }
    __syncthreads();
    for (int i = 0; i < 16; ++i) {
        const int e = i * 256 + (int)threadIdx.x;
        const int n = e >> 6, kk = e & 63;
        Wt[(size_t)(n0 + n) * 1024 + k0 + kk] = (bf16)T[n][kk];
    }
}

// ======================= V transpose ================================
__global__ void vtrans(const bf16* __restrict__ KV, bf16* __restrict__ Vt) {
    __shared__ bf16 T[64][66];
    const int bid = blockIdx.x;
    const int jt = bid % 12;
    const int h  = (bid / 12) & 15;
    const int bg = bid / 192;
    const int j0 = jt * 64;
    const bf16* src = KV + (size_t)bg * KVL * 2048 + 1024 + h * 64;
    for (int i = 0; i < 16; ++i) {
        const int e = i * 256 + (int)threadIdx.x;
        const int j = e >> 6, dd = e & 63;
        T[dd][j] = src[(size_t)(j0 + j) * 2048 + dd];
    }
    __syncthreads();
    bf16* dst = Vt + ((size_t)(bg * 16 + h)) * 64 * KVL;
    for (int i = 0; i < 16; ++i) {
        const int e = i * 256 + (int)threadIdx.x;
        const int d = e >> 6, jj = e & 63;
        dst[(size_t)d * KVL + j0 + jj] = T[d][jj];
    }
}

// ======================= 256x256 8-phase GEMM (K=1024 fixed) ========
// C[M][N] = A[M][K] * Bt[N][K]^T.  512 thr = 8 waves (2M x 4N), per-wave 128x64.
// LDS 128KB: A[2buf][2half][2wr][64][64] + B[2buf][2half][4wc][32][64], bf16.
// Swizzle: LDS granule h at row r holds source granule h^(r&7); reads XOR same key.
// vmcnt(6) at phases 4/8 only (3 half-tiles in flight).
#define PH_MID() do { \
    __builtin_amdgcn_s_barrier(); \
    asm volatile("s_waitcnt lgkmcnt(0)" ::: "memory"); \
    __builtin_amdgcn_sched_barrier(0); \
    __builtin_amdgcn_s_setprio(1); \
} while(0)

#define PH_END() do { \
    __builtin_amdgcn_s_setprio(0); \
    __builtin_amdgcn_sched_barrier(0); \
    __builtin_amdgcn_s_barrier(); \
} while(0)

#define VM6() asm volatile("s_waitcnt vmcnt(6)" ::: "memory")

#define STAGE_A(bufc, half, tile) do { \
    const bf16* s0_ = pA + (size_t)(half) * 64 * 1024 + (tile) * 64; \
    bf16* d0_ = ldsA + (bufc) * 16384 + (half) * 8192; \
    gload_lds16(s0_, d0_); \
    gload_lds16(s0_ + (size_t)128 * 1024, d0_ + 4096); \
} while(0)

#define STAGE_B(bufc, half, tile) do { \
    const bf16* s0_ = pB + (size_t)(half) * 32 * 1024 + (tile) * 64; \
    bf16* d0_ = ldsB + (bufc) * 16384 + (half) * 8192; \
    gload_lds16(s0_, d0_); \
    gload_lds16(s0_ + (size_t)128 * 1024, d0_ + 4096); \
} while(0)

#define LDA(bufc, mh) do { \
    const bf16* p_ = sm + (bufc) * 16384 + (mh) * 8192; \
    _Pragma("unroll") \
    for (int j_ = 0; j_ < 4; ++j_) { \
        a[j_][0] = *(const u32x4*)(p_ + j_ * 1024 + eA0); \
        a[j_][1] = *(const u32x4*)(p_ + j_ * 1024 + eA1); \
    } \
} while(0)

#define LDB(bufc, nh) do { \
    const bf16* p_ = sm + 32768 + (bufc) * 16384 + (nh) * 8192; \
    _Pragma("unroll") \
    for (int j_ = 0; j_ < 2; ++j_) { \
        b[(nh)*2 + j_][0] = *(const u32x4*)(p_ + j_ * 1024 + eB0); \
        b[(nh)*2 + j_][1] = *(const u32x4*)(p_ + j_ * 1024 + eB1); \
    } \
} while(0)

#define MM(mh, nh) do { \
    _Pragma("unroll") \
    for (int j_ = 0; j_ < 4; ++j_) { \
        _Pragma("unroll") \
        for (int i_ = 0; i_ < 2; ++i_) { \
            f32x4 c_ = acc[(mh)*4 + j_][(nh)*2 + i_]; \
            c_ = mfma16(as_bf(a[j_][0]), as_bf(b[(nh)*2 + i_][0]), c_); \
            c_ = mfma16(as_bf(a[j_][1]), as_bf(b[(nh)*2 + i_][1]), c_); \
            acc[(mh)*4 + j_][(nh)*2 + i_] = c_; \
        } \
    } \
} while(0)

template<int EPI>
__global__ __launch_bounds__(512) void gemm8(
    const bf16* __restrict__ A, const bf16* __restrict__ Bt,
    bf16* __restrict__ Cb, float* __restrict__ Cf,
    const float* __restrict__ bias, int N, int mt, int nwg)
{
    __shared__ bf16 sm[65536];   // A: [0,32768) elems, B: [32768,65536)
    const int tid = threadIdx.x, lane = tid & 63, wid = tid >> 6;

    // T1: bijective XCD swizzle
    int wg = blockIdx.x;
    {
        const int q = nwg >> 3, r = nwg & 7, xcd = wg & 7, off = wg >> 3;
        wg = (xcd < r ? xcd * (q + 1) : r * (q + 1) + (xcd - r) * q) + off;
    }
    const int bm = wg % mt, bn = wg / mt;
    const int wr = wid >> 2, wc = wid & 3;
    const int l15 = lane & 15, l4 = lane >> 4;

    // staging addressing: thread covers LDS row R=wid*8+lane/8, granule slot h=lane&7;
    // pre-swizzled global source granule G = h ^ (R&7), R&7 == lane>>3
    const int Rrow = (wid << 3) + (lane >> 3);
    const int G    = (lane & 7) ^ (lane >> 3);
    const bf16* pA = A  + (size_t)(bm * 256 + Rrow) * 1024 + G * 8;
    const int wc1 = Rrow >> 5, cc1 = Rrow & 31;
    const bf16* pB = Bt + (size_t)(bn * 256 + wc1 * 64 + cc1) * 1024 + G * 8;
    bf16* ldsA = sm + (wid << 9);
    bf16* ldsB = sm + 32768 + (wid << 9);

    // ds_read bases (elements), swizzled: granule g0 = l4 ^ (l15&7); ks=1 -> ^32
    const int g0  = l4 ^ (l15 & 7);
    const int eA0 = wr * 4096 + l15 * 64 + g0 * 8;
    const int eA1 = eA0 ^ 32;
    const int eB0 = wc * 2048 + l15 * 64 + g0 * 8;
    const int eB1 = eB0 ^ 32;

    f32x4 acc[8][4];
    u32x4 a[4][2], b[4][2];
    const f32x4 zf = {0.f, 0.f, 0.f, 0.f};
    #pragma unroll
    for (int m = 0; m < 8; ++m)
        #pragma unroll
        for (int n = 0; n < 4; ++n) acc[m][n] = zf;

    // prologue: tile0 (4 halves) + tile1 (3 halves); buf1.AH1(tile1) staged at ph1.
    STAGE_A(0, 0, 0); STAGE_B(0, 0, 0); STAGE_B(0, 1, 0); STAGE_A(0, 1, 0);
    STAGE_A(1, 0, 1); STAGE_B(1, 0, 1); STAGE_B(1, 1, 1);
    asm volatile("s_waitcnt vmcnt(6)" ::: "memory");
    __builtin_amdgcn_s_barrier();

    #pragma unroll 1
    for (int t = 0; t < 8; ++t) {
        const int T1 = 2 * t + 1;
        const int n0 = (2 * t + 2 < 15) ? 2 * t + 2 : 15;
        const int n1 = (2 * t + 3 < 15) ? 2 * t + 3 : 15;
        // ph1: compute buf0 quad(0,0)
        LDA(0, 0); LDB(0, 0); STAGE_A(1, 1, T1);
        PH_MID(); MM(0, 0); PH_END();
        // ph2: quad(0,1)
        LDB(0, 1); STAGE_A(0, 0, n0);
        PH_MID(); MM(0, 1); PH_END();
        // ph3: quad(1,0)
        LDA(0, 1); STAGE_B(0, 0, n0);
        PH_MID(); MM(1, 0); PH_END();
        // ph4: quad(1,1) + vmcnt guard for buf1 reads
        STAGE_B(0, 1, n0);
        PH_MID(); MM(1, 1); VM6(); PH_END();
        // ph5: compute buf1 quad(0,0)
        LDA(1, 0); LDB(1, 0); STAGE_A(0, 1, n0);
        PH_MID(); MM(0, 0); PH_END();
        // ph6: quad(0,1)
        LDB(1, 1); STAGE_A(1, 0, n1);
        PH_MID(); MM(0, 1); PH_END();
        // ph7: quad(1,0)
        LDA(1, 1); STAGE_B(1, 0, n1);
        PH_MID(); MM(1, 0); PH_END();
        // ph8: quad(1,1) + vmcnt guard for next-iter buf0 reads
        STAGE_B(1, 1, n1);
        PH_MID(); MM(1, 1); VM6(); PH_END();
    }
    asm volatile("s_waitcnt vmcnt(0)" ::: "memory");

    // epilogue: D frag col=l15, row=l4*4+r
    #pragma unroll
    for (int m = 0; m < 8; ++m) {
        const int row = bm * 256 + wr * 128 + m * 16 + l4 * 4;
        #pragma unroll
        for (int n = 0; n < 4; ++n) {
            const int col = bn * 256 + wc * 64 + n * 16 + l15;
            f32x4 v = acc[m][n];
            if (EPI == 0) {
                #pragma unroll
                for (int r = 0; r < 4; ++r)
                    Cb[(size_t)(row + r) * N + col] = (bf16)v[r];
            } else {
                const float bs = bias[col];
                #pragma unroll
                for (int r = 0; r < 4; ++r)
                    Cf[(size_t)(row + r) * N + col] = v[r] + bs;
            }
        }
    }
}

// ======================= flash attention (unchanged) =================
__global__ __launch_bounds__(256, 3) void attn_fwd(
    const bf16* __restrict__ Q, const bf16* __restrict__ KV,
    const bf16* __restrict__ Vt, bf16* __restrict__ O)
{
    __shared__ bf16 Kl[2][64][32];
    __shared__ bf16 Vl[2][64][32];
    __shared__ bf16 Pl[4][16][88];

    const int tid = threadIdx.x, lane = tid & 63, wid = tid >> 6;
    int bid = blockIdx.x;
    const int h = bid & 15; bid >>= 4;
    const int qt = bid % 44, b = bid / 44;
    const int chunk = qt < 28 ? (qt >> 2) : 7;
    const int qrow0 = b * (TOUT * S_) +
                      (qt < 28 ? chunk * S_ + (qt & 3) * 64 : 7 * S_ + (qt - 28) * 64);

    const bf16* kg = KV + ((size_t)(b * 8 + chunk) * KVL) * 2048 + h * 64;
    const bf16* vg = Vt + ((size_t)((b * 8 + chunk) * 16 + h)) * 64 * KVL;

    const int l15 = lane & 15, l4 = lane >> 4;

    const int qrow = qrow0 + wid * 16 + l15;
    const bf16* qp = Q + (size_t)qrow * D_ + h * 64 + l4 * 8;
    const u32x4 q0 = *(const u32x4*)qp;
    const u32x4 q1 = *(const u32x4*)(qp + 32);

    float m_r[4], l_r[4], al[4];
    f32x4 oacc[4];
    const f32x4 zf = {0.f, 0.f, 0.f, 0.f};
    #pragma unroll
    for (int r = 0; r < 4; ++r) { m_r[r] = -1e30f; l_r[r] = 0.f; }
    #pragma unroll
    for (int n = 0; n < 4; ++n) oacc[n] = zf;

    const int ii = wid * 64 + lane;
    const int srow = ii >> 2, sc = ii & 3;
    bf16* kld = &Kl[0][0][0] + wid * 512;
    bf16* vld = &Vl[0][0][0] + wid * 512;
    const float scale = 0.125f;

    for (int kt = 0; kt < 12; ++kt) {
        const int kv0 = kt * 64;
        __syncthreads();
        gload_lds16(kg + (size_t)(kv0 + srow) * 2048 + sc * 8,      kld);
        gload_lds16(kg + (size_t)(kv0 + srow) * 2048 + 32 + sc * 8, kld + 2048);
        gload_lds16(vg + (size_t)srow * KVL + kv0 + sc * 8,         vld);
        gload_lds16(vg + (size_t)srow * KVL + kv0 + 32 + sc * 8,    vld + 2048);
        __syncthreads();

        f32x4 s[4];
        #pragma unroll
        for (int n = 0; n < 4; ++n) {
            const bf16* kp = &Kl[0][n * 16 + l15][l4 * 8];
            const u32x4 b0 = *(const u32x4*)kp;
            const u32x4 b1 = *(const u32x4*)(kp + 2048);
            f32x4 t = mfma16(as_bf(q0), as_bf(b0), zf);
            s[n] = mfma16(as_bf(q1), as_bf(b1), t);
        }

        #pragma unroll
        for (int r = 0; r < 4; ++r) {
            float v = fmaxf(fmaxf(s[0][r], s[1][r]), fmaxf(s[2][r], s[3][r]));
            #pragma unroll
            for (int off = 1; off <= 8; off <<= 1)
                v = fmaxf(v, __shfl_xor(v, off));
            const float mn = fmaxf(m_r[r], v * scale);
            al[r] = __expf(m_r[r] - mn);
            m_r[r] = mn;
            const float p0 = __expf(s[0][r] * scale - mn);
            const float p1 = __expf(s[1][r] * scale - mn);
            const float p2 = __expf(s[2][r] * scale - mn);
            const float p3 = __expf(s[3][r] * scale - mn);
            float sum = p0 + p1 + p2 + p3;
            #pragma unroll
            for (int off = 1; off <= 8; off <<= 1)
                sum += __shfl_xor(sum, off);
            l_r[r] = l_r[r] * al[r] + sum;
            Pl[wid][l4 * 4 + r][l15]      = (bf16)p0;
            Pl[wid][l4 * 4 + r][16 + l15] = (bf16)p1;
            Pl[wid][l4 * 4 + r][32 + l15] = (bf16)p2;
            Pl[wid][l4 * 4 + r][48 + l15] = (bf16)p3;
        }
        #pragma unroll
        for (int n = 0; n < 4; ++n)
            #pragma unroll
            for (int r = 0; r < 4; ++r) oacc[n][r] *= al[r];

        asm volatile("s_waitcnt lgkmcnt(0)" ::: "memory");

        #pragma unroll
        for (int kk = 0; kk < 2; ++kk) {
            const u32x4 pa = *(const u32x4*)(&Pl[wid][l15][kk * 32 + l4 * 8]);
            #pragma unroll
            for (int n = 0; n < 4; ++n) {
                const u32x4 bv = *(const u32x4*)(&Vl[kk][n * 16 + l15][l4 * 8]);
                oacc[n] = mfma16(as_bf(pa), as_bf(bv), oacc[n]);
            }
        }
    }

    #pragma unroll
    for (int r = 0; r < 4; ++r) {
        const float inv = 1.f / l_r[r];
        const size_t row = (size_t)(qrow0 + wid * 16 + l4 * 4 + r) * D_;
        #pragma unroll
        for (int n = 0; n < 4; ++n)
            O[row + h * 64 + n * 16 + l15] = (bf16)(oacc[n][r] * inv);
    }
}

// ======================= launch =====================================
extern "C" void kernel_launch(void* const* d_in, const int* in_sizes, int n_in,
                              void* d_out, int out_size, void* d_ws, size_t ws_size,
                              hipStream_t stream) {
    (void)in_sizes; (void)n_in; (void)out_size; (void)ws_size;
    const float* x    = (const float*)d_in[0];
    const float* Wqkv = (const float*)d_in[1];
    const float* Wout = (const float*)d_in[2];
    const float* bout = (const float*)d_in[3];

    bf16* Aq     = (bf16*)d_ws;
    bf16* Akv    = Aq     + (size_t)MQ  * 1024;
    bf16* Wqkv_t = Akv    + (size_t)MKV * 1024;
    bf16* Wout_t = Wqkv_t + (size_t)3072 * 1024;
    bf16* Qb     = Wout_t + (size_t)1024 * 1024;
    bf16* KVb    = Qb     + (size_t)MQ  * 1024;
    bf16* Vtb    = Akv;
    bf16* Ob     = Aq;

    gather_q <<<MQ  * 128 / 256, 256, 0, stream>>>(x, Aq);
    gather_kv<<<MKV * 128 / 256, 256, 0, stream>>>(x, Akv);
    wtrans<<<16 * 48, 256, 0, stream>>>(Wqkv, Wqkv_t, 3072);
    wtrans<<<16 * 16, 256, 0, stream>>>(Wout, Wout_t, 1024);

    gemm8<0><<<176, 512, 0, stream>>>(Aq, Wqkv_t, Qb, nullptr, nullptr,
                                      1024, 44, 176);
    gemm8<0><<<768, 512, 0, stream>>>(Akv, Wqkv_t + (size_t)1024 * 1024, KVb,
                                      nullptr, nullptr, 2048, 96, 768);

    vtrans<<<32 * 16 * 12, 256, 0, stream>>>(KVb, Vtb);
    attn_fwd<<<4 * 44 * 16, 256, 0, stream>>>(Qb, KVb, Vtb, Ob);

    gemm8<1><<<176, 512, 0, stream>>>(Ob, Wout_t, nullptr, (float*)d_out, bout,
                                      1024, 44, 176);
}

// Round 3
// 316.249 us; speedup vs baseline: 1.1712x; 1.1143x over previous
//
// MemFullAttention_19585050870313 — MI355X round 3
// Change: rewrite attn_fwd with swapped QK^T (S^T via mfma(K,Q)) -> in-lane softmax
// (2 shuffles vs 32), transposed PV (O^T = Vt*P^T, lane-local rescale), cvt_pk +
// ds_bpermute P redistribution, XOR-swizzled K/V LDS (both-sides, rule #21),
// double-buffered K/V with single barrier/tile, LDS-transpose epilogue.
// GEMMs (8-phase 256^2), gathers, transposes unchanged from round 2.
#include <hip/hip_runtime.h>
#include <hip/hip_bf16.h>

typedef __bf16 bf16;
typedef __bf16 bf16x8 __attribute__((ext_vector_type(8)));
typedef float  f32x4  __attribute__((ext_vector_type(4)));
typedef float  f32x4v __attribute__((ext_vector_type(4)));
typedef unsigned int u32x4 __attribute__((ext_vector_type(4)));

#define DEV __device__ __forceinline__

DEV void gload_lds16(const bf16* g, bf16* l) {
    __builtin_amdgcn_global_load_lds(
        (__attribute__((address_space(1))) void*)g,
        (__attribute__((address_space(3))) void*)l, 16, 0, 0);
}

DEV bf16x8 as_bf(u32x4 v) { return __builtin_bit_cast(bf16x8, v); }

DEV f32x4 mfma16(bf16x8 a, bf16x8 b, f32x4 c) {
    return __builtin_amdgcn_mfma_f32_16x16x32_bf16(a, b, c, 0, 0, 0);
}

DEV int cvtpk(float lo, float hi) {
    int r;
    asm("v_cvt_pk_bf16_f32 %0, %1, %2" : "=v"(r) : "v"(lo), "v"(hi));
    return r;
}

// ---- problem constants (reference_length fixed at 3) ----
constexpr int D_   = 1024;
constexpr int S_   = 256;
constexpr int TOUT = 11;
constexpr int MQ   = 4 * TOUT * S_;   // 11264
constexpr int MKV  = 4 * 8 * 3 * S_;  // 24576
constexpr int KVL  = 768;

// ======================= gather + cast kernels =======================
__global__ void gather_q(const float* __restrict__ x, bf16* __restrict__ Aq) {
    const int idx  = blockIdx.x * 256 + threadIdx.x;
    const int row  = idx >> 7, part = idx & 127;
    const int b    = row / (TOUT * S_);
    const int r2   = row - b * (TOUT * S_);
    const int tout = r2 >> 8;
    const int s    = r2 & 255;
    const int tx   = tout < 7 ? tout * 4 : 28 + (tout - 7);
    const float* src = x + ((size_t)((b * 32 + tx) * S_ + s)) * D_ + part * 8;
    f32x4v v0 = *(const f32x4v*)src;
    f32x4v v1 = *(const f32x4v*)(src + 4);
    bf16x8 o;
    o[0]=(bf16)v0[0]; o[1]=(bf16)v0[1]; o[2]=(bf16)v0[2]; o[3]=(bf16)v0[3];
    o[4]=(bf16)v1[0]; o[5]=(bf16)v1[1]; o[6]=(bf16)v1[2]; o[7]=(bf16)v1[3];
    *(bf16x8*)(Aq + (size_t)row * D_ + part * 8) = o;
}

__global__ void gather_kv(const float* __restrict__ x, bf16* __restrict__ Akv) {
    const int idx = blockIdx.x * 256 + threadIdx.x;
    const int row = idx >> 7, part = idx & 127;
    const int b   = row / 6144;
    const int r2  = row - b * 6144;
    const int c   = r2 / KVL;
    const int j   = r2 - c * KVL;
    const int f   = 1 + (j >> 8);
    const int s   = j & 255;
    const int tx  = c * 4 + f;
    const float* src = x + ((size_t)((b * 32 + tx) * S_ + s)) * D_ + part * 8;
    f32x4v v0 = *(const f32x4v*)src;
    f32x4v v1 = *(const f32x4v*)(src + 4);
    bf16x8 o;
    o[0]=(bf16)v0[0]; o[1]=(bf16)v0[1]; o[2]=(bf16)v0[2]; o[3]=(bf16)v0[3];
    o[4]=(bf16)v1[0]; o[5]=(bf16)v1[1]; o[6]=(bf16)v1[2]; o[7]=(bf16)v1[3];
    *(bf16x8*)(Akv + (size_t)row * D_ + part * 8) = o;
}

// ======================= weight transpose ===========================
__global__ void wtrans(const float* __restrict__ W, bf16* __restrict__ Wt, int N) {
    __shared__ float T[64][65];
    const int bid = blockIdx.x;
    const int kt = bid & 15, nt = bid >> 4;
    const int k0 = kt * 64, n0 = nt * 64;
    for (int i = 0; i < 16; ++i) {
        const int e = i * 256 + (int)threadIdx.x;
        const int kk = e >> 6, nn = e & 63;
        T[nn][kk] = W[(size_t)(k0 + kk) * N + n0 + nn];
    }
    __syncthreads();
    for (int i = 0; i < 16; ++i) {
        const int e = i * 256 + (int)threadIdx.x;
        const int n = e >> 6, kk = e & 63;
        Wt[(size_t)(n0 + n) * 1024 + k0 + kk] = (bf16)T[n][kk];
    }
}

// ======================= V transpose ================================
__global__ void vtrans(const bf16* __restrict__ KV, bf16* __restrict__ Vt) {
    __shared__ bf16 T[64][66];
    const int bid = blockIdx.x;
    const int jt = bid % 12;
    const int h  = (bid / 12) & 15;
    const int bg = bid / 192;
    const int j0 = jt * 64;
    const bf16* src = KV + (size_t)bg * KVL * 2048 + 1024 + h * 64;
    for (int i = 0; i < 16; ++i) {
        const int e = i * 256 + (int)threadIdx.x;
        const int j = e >> 6, dd = e & 63;
        T[dd][j] = src[(size_t)(j0 + j) * 2048 + dd];
    }
    __syncthreads();
    bf16* dst = Vt + ((size_t)(bg * 16 + h)) * 64 * KVL;
    for (int i = 0; i < 16; ++i) {
        const int e = i * 256 + (int)threadIdx.x;
        const int d = e >> 6, jj = e & 63;
        dst[(size_t)d * KVL + j0 + jj] = T[d][jj];
    }
}

// ======================= 256x256 8-phase GEMM (unchanged, K=1024) ===
#define PH_MID() do { \
    __builtin_amdgcn_s_barrier(); \
    asm volatile("s_waitcnt lgkmcnt(0)" ::: "memory"); \
    __builtin_amdgcn_sched_barrier(0); \
    __builtin_amdgcn_s_setprio(1); \
} while(0)

#define PH_END() do { \
    __builtin_amdgcn_s_setprio(0); \
    __builtin_amdgcn_sched_barrier(0); \
    __builtin_amdgcn_s_barrier(); \
} while(0)

#define VM6() asm volatile("s_waitcnt vmcnt(6)" ::: "memory")

#define STAGE_A(bufc, half, tile) do { \
    const bf16* s0_ = pA + (size_t)(half) * 64 * 1024 + (tile) * 64; \
    bf16* d0_ = ldsA + (bufc) * 16384 + (half) * 8192; \
    gload_lds16(s0_, d0_); \
    gload_lds16(s0_ + (size_t)128 * 1024, d0_ + 4096); \
} while(0)

#define STAGE_B(bufc, half, tile) do { \
    const bf16* s0_ = pB + (size_t)(half) * 32 * 1024 + (tile) * 64; \
    bf16* d0_ = ldsB + (bufc) * 16384 + (half) * 8192; \
    gload_lds16(s0_, d0_); \
    gload_lds16(s0_ + (size_t)128 * 1024, d0_ + 4096); \
} while(0)

#define LDA(bufc, mh) do { \
    const bf16* p_ = sm + (bufc) * 16384 + (mh) * 8192; \
    _Pragma("unroll") \
    for (int j_ = 0; j_ < 4; ++j_) { \
        a[j_][0] = *(const u32x4*)(p_ + j_ * 1024 + eA0); \
        a[j_][1] = *(const u32x4*)(p_ + j_ * 1024 + eA1); \
    } \
} while(0)

#define LDB(bufc, nh) do { \
    const bf16* p_ = sm + 32768 + (bufc) * 16384 + (nh) * 8192; \
    _Pragma("unroll") \
    for (int j_ = 0; j_ < 2; ++j_) { \
        b[(nh)*2 + j_][0] = *(const u32x4*)(p_ + j_ * 1024 + eB0); \
        b[(nh)*2 + j_][1] = *(const u32x4*)(p_ + j_ * 1024 + eB1); \
    } \
} while(0)

#define MM(mh, nh) do { \
    _Pragma("unroll") \
    for (int j_ = 0; j_ < 4; ++j_) { \
        _Pragma("unroll") \
        for (int i_ = 0; i_ < 2; ++i_) { \
            f32x4 c_ = acc[(mh)*4 + j_][(nh)*2 + i_]; \
            c_ = mfma16(as_bf(a[j_][0]), as_bf(b[(nh)*2 + i_][0]), c_); \
            c_ = mfma16(as_bf(a[j_][1]), as_bf(b[(nh)*2 + i_][1]), c_); \
            acc[(mh)*4 + j_][(nh)*2 + i_] = c_; \
        } \
    } \
} while(0)

template<int EPI>
__global__ __launch_bounds__(512) void gemm8(
    const bf16* __restrict__ A, const bf16* __restrict__ Bt,
    bf16* __restrict__ Cb, float* __restrict__ Cf,
    const float* __restrict__ bias, int N, int mt, int nwg)
{
    __shared__ bf16 sm[65536];
    const int tid = threadIdx.x, lane = tid & 63, wid = tid >> 6;

    int wg = blockIdx.x;
    {
        const int q = nwg >> 3, r = nwg & 7, xcd = wg & 7, off = wg >> 3;
        wg = (xcd < r ? xcd * (q + 1) : r * (q + 1) + (xcd - r) * q) + off;
    }
    const int bm = wg % mt, bn = wg / mt;
    const int wr = wid >> 2, wc = wid & 3;
    const int l15 = lane & 15, l4 = lane >> 4;

    const int Rrow = (wid << 3) + (lane >> 3);
    const int G    = (lane & 7) ^ (lane >> 3);
    const bf16* pA = A  + (size_t)(bm * 256 + Rrow) * 1024 + G * 8;
    const int wc1 = Rrow >> 5, cc1 = Rrow & 31;
    const bf16* pB = Bt + (size_t)(bn * 256 + wc1 * 64 + cc1) * 1024 + G * 8;
    bf16* ldsA = sm + (wid << 9);
    bf16* ldsB = sm + 32768 + (wid << 9);

    const int g0  = l4 ^ (l15 & 7);
    const int eA0 = wr * 4096 + l15 * 64 + g0 * 8;
    const int eA1 = eA0 ^ 32;
    const int eB0 = wc * 2048 + l15 * 64 + g0 * 8;
    const int eB1 = eB0 ^ 32;

    f32x4 acc[8][4];
    u32x4 a[4][2], b[4][2];
    const f32x4 zf = {0.f, 0.f, 0.f, 0.f};
    #pragma unroll
    for (int m = 0; m < 8; ++m)
        #pragma unroll
        for (int n = 0; n < 4; ++n) acc[m][n] = zf;

    STAGE_A(0, 0, 0); STAGE_B(0, 0, 0); STAGE_B(0, 1, 0); STAGE_A(0, 1, 0);
    STAGE_A(1, 0, 1); STAGE_B(1, 0, 1); STAGE_B(1, 1, 1);
    asm volatile("s_waitcnt vmcnt(6)" ::: "memory");
    __builtin_amdgcn_s_barrier();

    #pragma unroll 1
    for (int t = 0; t < 8; ++t) {
        const int T1 = 2 * t + 1;
        const int n0 = (2 * t + 2 < 15) ? 2 * t + 2 : 15;
        const int n1 = (2 * t + 3 < 15) ? 2 * t + 3 : 15;
        LDA(0, 0); LDB(0, 0); STAGE_A(1, 1, T1);
        PH_MID(); MM(0, 0); PH_END();
        LDB(0, 1); STAGE_A(0, 0, n0);
        PH_MID(); MM(0, 1); PH_END();
        LDA(0, 1); STAGE_B(0, 0, n0);
        PH_MID(); MM(1, 0); PH_END();
        STAGE_B(0, 1, n0);
        PH_MID(); MM(1, 1); VM6(); PH_END();
        LDA(1, 0); LDB(1, 0); STAGE_A(0, 1, n0);
        PH_MID(); MM(0, 0); PH_END();
        LDB(1, 1); STAGE_A(1, 0, n1);
        PH_MID(); MM(0, 1); PH_END();
        LDA(1, 1); STAGE_B(1, 0, n1);
        PH_MID(); MM(1, 0); PH_END();
        STAGE_B(1, 1, n1);
        PH_MID(); MM(1, 1); VM6(); PH_END();
    }
    asm volatile("s_waitcnt vmcnt(0)" ::: "memory");

    #pragma unroll
    for (int m = 0; m < 8; ++m) {
        const int row = bm * 256 + wr * 128 + m * 16 + l4 * 4;
        #pragma unroll
        for (int n = 0; n < 4; ++n) {
            const int col = bn * 256 + wc * 64 + n * 16 + l15;
            f32x4 v = acc[m][n];
            if (EPI == 0) {
                #pragma unroll
                for (int r = 0; r < 4; ++r)
                    Cb[(size_t)(row + r) * N + col] = (bf16)v[r];
            } else {
                const float bs = bias[col];
                #pragma unroll
                for (int r = 0; r < 4; ++r)
                    Cf[(size_t)(row + r) * N + col] = v[r] + bs;
            }
        }
    }
}

// ======================= flash attention (round-3 rewrite) ==========
// block = (b, chunk, qtile64, head); 4 waves x 16 q-rows.
// Swapped QK^T: S^T = K·Q^T -> lane (l4,l15) holds S[q=l15][key=n*16+l4*4+r].
// Softmax: in-lane over 16 keys + 2 shfl_xor (16,32) across l4 groups.
// PV transposed: O^T = Vt·P^T (A=Vt frag, B=P^T frag) -> q stays lane-local.
// P^T B-frag built via 8 cvt_pk + 16 ds_bpermute + 8 cndmask per tile:
//   dst word W <- src lane (2*(L4&1)+(W>>1))*16+l15, reg u[kk*2+(L4>>1)][W&1].
// K/V LDS XOR-swizzled (granule ^= (row>>1)&3) on BOTH stage-source and read.
// Double-buffered K/V, one barrier per tile. O stored via LDS transpose.
__global__ __launch_bounds__(256, 4) void attn_fwd(
    const bf16* __restrict__ Q, const bf16* __restrict__ KV,
    const bf16* __restrict__ Vt, bf16* __restrict__ O)
{
    __shared__ bf16 Kl[2][2][64][32];   // [buf][k-half][key][32]
    __shared__ bf16 Vl[2][2][64][32];   // [buf][kv-half][d][32]

    const int tid = threadIdx.x, lane = tid & 63, wid = tid >> 6;
    int bid = blockIdx.x;
    const int h = bid & 15; bid >>= 4;
    const int qt = bid % 44, b = bid / 44;
    const int chunk = qt < 28 ? (qt >> 2) : 7;
    const int qrow0 = b * (TOUT * S_) +
                      (qt < 28 ? chunk * S_ + (qt & 3) * 64 : 7 * S_ + (qt - 28) * 64);

    const bf16* kg = KV + ((size_t)(b * 8 + chunk) * KVL) * 2048 + h * 64;
    const bf16* vg = Vt + ((size_t)((b * 8 + chunk) * 16 + h)) * 64 * KVL;

    const int l15 = lane & 15, l4 = lane >> 4;

    // Q as MFMA B-operand: lane holds Q[q=l15][k=l4*8+j]; fold scale=0.125 (pow2, exact)
    const bf16* qp = Q + (size_t)(qrow0 + wid * 16 + l15) * D_ + h * 64 + l4 * 8;
    u32x4 q0, q1;
    {
        bf16x8 t0 = *(const bf16x8*)qp;
        bf16x8 t1 = *(const bf16x8*)(qp + 32);
        #pragma unroll
        for (int j = 0; j < 8; ++j) {
            t0[j] = (bf16)((float)t0[j] * 0.125f);
            t1[j] = (bf16)((float)t1[j] * 0.125f);
        }
        q0 = __builtin_bit_cast(u32x4, t0);
        q1 = __builtin_bit_cast(u32x4, t1);
    }

    // staging: wave-linear dest; pre-swizzled source granule (rule #21 both-sides)
    const int R   = wid * 16 + (lane >> 2);                 // LDS row this thread fills
    const int gsw = ((lane & 3) ^ ((lane >> 3) & 3)) * 8;   // swizzled src granule (elems)
    // read-side swizzled granule: row = *16 + l15 -> key (row>>1)&3 == (l15>>1)&3
    const int rg  = (l4 ^ ((l15 >> 1) & 3)) * 8;

    const int baseA = ((2 * (l4 & 1)) * 16 + l15) * 4;  // bpermute src-lane byte addr, W=0,1
    const int baseB = baseA + 64;                        // W=2,3
    const bool hi2 = (l4 & 2) != 0;

    float m_s = -1e30f, l_s = 0.f;
    f32x4 oacc[4];
    const f32x4 zf = {0.f, 0.f, 0.f, 0.f};
    #pragma unroll
    for (int m2 = 0; m2 < 4; ++m2) oacc[m2] = zf;

#define ASTAGE(c, t) do { \
    const int kv0_ = (t) * 64; \
    gload_lds16(kg + (size_t)(kv0_ + R) * 2048 + gsw,      &Kl[c][0][0][0] + wid * 512); \
    gload_lds16(kg + (size_t)(kv0_ + R) * 2048 + 32 + gsw, &Kl[c][1][0][0] + wid * 512); \
    gload_lds16(vg + (size_t)R * KVL + kv0_ + gsw,         &Vl[c][0][0][0] + wid * 512); \
    gload_lds16(vg + (size_t)R * KVL + kv0_ + 32 + gsw,    &Vl[c][1][0][0] + wid * 512); \
} while (0)

    ASTAGE(0, 0);
    __syncthreads();

    #pragma unroll 1
    for (int kt = 0; kt < 12; ++kt) {
        const int cur = kt & 1;
        if (kt < 11) ASTAGE(cur ^ 1, kt + 1);

        // S^T = K · Q^T (A=K frag, B=Q frag)
        f32x4 s[4];
        #pragma unroll
        for (int n = 0; n < 4; ++n) {
            const bf16* kp = &Kl[cur][0][n * 16 + l15][0] + rg;
            const u32x4 k0 = *(const u32x4*)kp;
            const u32x4 k1 = *(const u32x4*)(kp + 2048);
            f32x4 t = mfma16(as_bf(k0), as_bf(q0), zf);
            s[n] = mfma16(as_bf(k1), as_bf(q1), t);
        }

        // online softmax, mostly in-lane (16 keys/lane), 2 shuffles across l4 groups
        float pm = s[0][0];
        #pragma unroll
        for (int n = 0; n < 4; ++n)
            #pragma unroll
            for (int r = 0; r < 4; ++r) pm = fmaxf(pm, s[n][r]);
        pm = fmaxf(pm, __shfl_xor(pm, 16));
        pm = fmaxf(pm, __shfl_xor(pm, 32));
        const float mn = fmaxf(m_s, pm);
        const float al = __expf(m_s - mn);
        m_s = mn;
        float p[4][4];
        float sum = 0.f;
        #pragma unroll
        for (int n = 0; n < 4; ++n)
            #pragma unroll
            for (int r = 0; r < 4; ++r) {
                const float e = __expf(s[n][r] - mn);
                p[n][r] = e; sum += e;
            }
        sum += __shfl_xor(sum, 16);
        sum += __shfl_xor(sum, 32);
        l_s = l_s * al + sum;
        #pragma unroll
        for (int m2 = 0; m2 < 4; ++m2) oacc[m2] *= al;

        // pack P to bf16 pairs: u[n][w] holds keys n*16 + l4*4 + 2w,2w+1
        int u[4][2];
        #pragma unroll
        for (int n = 0; n < 4; ++n) {
            u[n][0] = cvtpk(p[n][0], p[n][1]);
            u[n][1] = cvtpk(p[n][2], p[n][3]);
        }

        // redistribute to B-frag layout + PV (O^T accumulate)
        #pragma unroll
        for (int kk = 0; kk < 2; ++kk) {
            const int e0 = __builtin_amdgcn_ds_bpermute(baseA, u[2 * kk][0]);
            const int f0 = __builtin_amdgcn_ds_bpermute(baseA, u[2 * kk + 1][0]);
            const int e1 = __builtin_amdgcn_ds_bpermute(baseA, u[2 * kk][1]);
            const int f1 = __builtin_amdgcn_ds_bpermute(baseA, u[2 * kk + 1][1]);
            const int e2 = __builtin_amdgcn_ds_bpermute(baseB, u[2 * kk][0]);
            const int f2 = __builtin_amdgcn_ds_bpermute(baseB, u[2 * kk + 1][0]);
            const int e3 = __builtin_amdgcn_ds_bpermute(baseB, u[2 * kk][1]);
            const int f3 = __builtin_amdgcn_ds_bpermute(baseB, u[2 * kk + 1][1]);
            u32x4 pb;
            pb[0] = (unsigned)(hi2 ? f0 : e0);
            pb[1] = (unsigned)(hi2 ? f1 : e1);
            pb[2] = (unsigned)(hi2 ? f2 : e2);
            pb[3] = (unsigned)(hi2 ? f3 : e3);
            #pragma unroll
            for (int m2 = 0; m2 < 4; ++m2) {
                const u32x4 vf = *(const u32x4*)(&Vl[cur][kk][m2 * 16 + l15][0] + rg);
                oacc[m2] = mfma16(as_bf(vf), as_bf(pb), oacc[m2]);
            }
        }
        __syncthreads();   // next-tile DMA landed (vmcnt drained) + all reads of cur done
    }
#undef ASTAGE

    // epilogue: O^T frag -> LDS transpose (per-wave region) -> coalesced O rows
    const float inv = 1.f / l_s;
    bf16* sc = &Kl[0][0][0][0] + wid * 1152;   // [16 q][72] bf16 per wave
    #pragma unroll
    for (int m2 = 0; m2 < 4; ++m2)
        #pragma unroll
        for (int r = 0; r < 4; ++r)
            sc[l15 * 72 + m2 * 16 + l4 * 4 + r] = (bf16)(oacc[m2][r] * inv);
    const int rq = lane >> 2, rd = (lane & 3) * 16;
    const bf16* sr = sc + rq * 72 + rd;
    const u32x4 o0 = *(const u32x4*)sr;
    const u32x4 o1 = *(const u32x4*)(sr + 8);
    bf16* op = O + (size_t)(qrow0 + wid * 16 + rq) * D_ + h * 64 + rd;
    *(u32x4*)op = o0;
    *(u32x4*)(op + 8) = o1;
}

// ======================= launch =====================================
extern "C" void kernel_launch(void* const* d_in, const int* in_sizes, int n_in,
                              void* d_out, int out_size, void* d_ws, size_t ws_size,
                              hipStream_t stream) {
    (void)in_sizes; (void)n_in; (void)out_size; (void)ws_size;
    const float* x    = (const float*)d_in[0];
    const float* Wqkv = (const float*)d_in[1];
    const float* Wout = (const float*)d_in[2];
    const float* bout = (const float*)d_in[3];

    bf16* Aq     = (bf16*)d_ws;
    bf16* Akv    = Aq     + (size_t)MQ  * 1024;
    bf16* Wqkv_t = Akv    + (size_t)MKV * 1024;
    bf16* Wout_t = Wqkv_t + (size_t)3072 * 1024;
    bf16* Qb     = Wout_t + (size_t)1024 * 1024;
    bf16* KVb    = Qb     + (size_t)MQ  * 1024;
    bf16* Vtb    = Akv;
    bf16* Ob     = Aq;

    gather_q <<<MQ  * 128 / 256, 256, 0, stream>>>(x, Aq);
    gather_kv<<<MKV * 128 / 256, 256, 0, stream>>>(x, Akv);
    wtrans<<<16 * 48, 256, 0, stream>>>(Wqkv, Wqkv_t, 3072);
    wtrans<<<16 * 16, 256, 0, stream>>>(Wout, Wout_t, 1024);

    gemm8<0><<<176, 512, 0, stream>>>(Aq, Wqkv_t, Qb, nullptr, nullptr,
                                      1024, 44, 176);
    gemm8<0><<<768, 512, 0, stream>>>(Akv, Wqkv_t + (size_t)1024 * 1024, KVb,
                                      nullptr, nullptr, 2048, 96, 768);

    vtrans<<<32 * 16 * 12, 256, 0, stream>>>(KVb, Vtb);
    attn_fwd<<<4 * 44 * 16, 256, 0, stream>>>(Qb, KVb, Vtb, Ob);

    gemm8<1><<<176, 512, 0, stream>>>(Ob, Wout_t, nullptr, (float*)d_out, bout,
                                      1024, 44, 176);
}

// Round 4
// 308.442 us; speedup vs baseline: 1.2009x; 1.0253x over previous
//
// MemFullAttention_19585050870313 — MI355X round 4
// Changes vs round 3:
//  - vtrans ELIMINATED: KV GEMM epilogue writes V directly transposed
//    ([bg*16+h][d][768] layout) via 8B ushort4 stores; K gets own [24576][1024] buf.
//  - Q GEMM + KV GEMM fused into one 944-block dispatch (no idle-CU window).
//  - gathers + weight transposes fused into one prep dispatch.
//  - attn unchanged except K stride 2048->1024.
#include <hip/hip_runtime.h>
#include <hip/hip_bf16.h>

typedef __bf16 bf16;
typedef __bf16 bf16x8 __attribute__((ext_vector_type(8)));
typedef float  f32x4  __attribute__((ext_vector_type(4)));
typedef float  f32x4v __attribute__((ext_vector_type(4)));
typedef unsigned int u32x4 __attribute__((ext_vector_type(4)));
typedef unsigned short u16x4 __attribute__((ext_vector_type(4)));

#define DEV __device__ __forceinline__

DEV void gload_lds16(const bf16* g, bf16* l) {
    __builtin_amdgcn_global_load_lds(
        (__attribute__((address_space(1))) void*)g,
        (__attribute__((address_space(3))) void*)l, 16, 0, 0);
}

DEV bf16x8 as_bf(u32x4 v) { return __builtin_bit_cast(bf16x8, v); }

DEV f32x4 mfma16(bf16x8 a, bf16x8 b, f32x4 c) {
    return __builtin_amdgcn_mfma_f32_16x16x32_bf16(a, b, c, 0, 0, 0);
}

DEV int cvtpk(float lo, float hi) {
    int r;
    asm("v_cvt_pk_bf16_f32 %0, %1, %2" : "=v"(r) : "v"(lo), "v"(hi));
    return r;
}

// ---- problem constants (reference_length fixed at 3) ----
constexpr int D_   = 1024;
constexpr int S_   = 256;
constexpr int TOUT = 11;
constexpr int MQ   = 4 * TOUT * S_;   // 11264
constexpr int MKV  = 4 * 8 * 3 * S_;  // 24576
constexpr int KVL  = 768;

// prep grid layout
constexpr int PB_WQKV = 768;                 // wtrans Wqkv blocks
constexpr int PB_WOUT = 256;                 // wtrans Wout blocks
constexpr int PB_GQ   = MQ  * 128 / 256;     // 5632
constexpr int PB_GKV  = MKV * 128 / 256;     // 12288
constexpr int PB_TOT  = PB_WQKV + PB_WOUT + PB_GQ + PB_GKV;   // 18944

// ======================= fused prep: wtrans x2 + gather x2 ==========
__global__ void prep(const float* __restrict__ x,
                     const float* __restrict__ Wqkv,
                     const float* __restrict__ Wout,
                     bf16* __restrict__ Aq, bf16* __restrict__ Akv,
                     bf16* __restrict__ Wqkv_t, bf16* __restrict__ Wout_t)
{
    __shared__ float T[64][65];
    const int tid = threadIdx.x;
    int wg = blockIdx.x;

    if (wg < PB_WQKV + PB_WOUT) {
        // weight transpose: f32 W[1024][N] -> bf16 Wt[N][1024]
        const float* W; bf16* Wt; int N, bid2;
        if (wg < PB_WQKV) { W = Wqkv; Wt = Wqkv_t; N = 3072; bid2 = wg; }
        else              { W = Wout; Wt = Wout_t; N = 1024; bid2 = wg - PB_WQKV; }
        const int kt = bid2 & 15, nt = bid2 >> 4;
        const int k0 = kt * 64, n0 = nt * 64;
        for (int i = 0; i < 16; ++i) {
            const int e = i * 256 + tid;
            const int kk = e >> 6, nn = e & 63;
            T[nn][kk] = W[(size_t)(k0 + kk) * N + n0 + nn];
        }
        __syncthreads();
        for (int i = 0; i < 16; ++i) {
            const int e = i * 256 + tid;
            const int n = e >> 6, kk = e & 63;
            Wt[(size_t)(n0 + n) * 1024 + k0 + kk] = (bf16)T[n][kk];
        }
        return;
    }
    wg -= PB_WQKV + PB_WOUT;

    int row, part;
    const float* src;
    bf16* dst;
    if (wg < PB_GQ) {
        const int idx = wg * 256 + tid;
        row = idx >> 7; part = idx & 127;
        const int b    = row / (TOUT * S_);
        const int r2   = row - b * (TOUT * S_);
        const int tout = r2 >> 8;
        const int s    = r2 & 255;
        const int tx   = tout < 7 ? tout * 4 : 28 + (tout - 7);
        src = x + ((size_t)((b * 32 + tx) * S_ + s)) * D_ + part * 8;
        dst = Aq + (size_t)row * D_ + part * 8;
    } else {
        const int idx = (wg - PB_GQ) * 256 + tid;
        row = idx >> 7; part = idx & 127;
        const int b  = row / 6144;
        const int r2 = row - b * 6144;
        const int c  = r2 / KVL;
        const int j  = r2 - c * KVL;
        const int f  = 1 + (j >> 8);
        const int s  = j & 255;
        const int tx = c * 4 + f;
        src = x + ((size_t)((b * 32 + tx) * S_ + s)) * D_ + part * 8;
        dst = Akv + (size_t)row * D_ + part * 8;
    }
    f32x4v v0 = *(const f32x4v*)src;
    f32x4v v1 = *(const f32x4v*)(src + 4);
    bf16x8 o;
    o[0]=(bf16)v0[0]; o[1]=(bf16)v0[1]; o[2]=(bf16)v0[2]; o[3]=(bf16)v0[3];
    o[4]=(bf16)v1[0]; o[5]=(bf16)v1[1]; o[6]=(bf16)v1[2]; o[7]=(bf16)v1[3];
    *(bf16x8*)dst = o;
}

// ======================= 8-phase 256x256 GEMM machinery =============
#define PH_MID() do { \
    __builtin_amdgcn_s_barrier(); \
    asm volatile("s_waitcnt lgkmcnt(0)" ::: "memory"); \
    __builtin_amdgcn_sched_barrier(0); \
    __builtin_amdgcn_s_setprio(1); \
} while(0)

#define PH_END() do { \
    __builtin_amdgcn_s_setprio(0); \
    __builtin_amdgcn_sched_barrier(0); \
    __builtin_amdgcn_s_barrier(); \
} while(0)

#define VM6() asm volatile("s_waitcnt vmcnt(6)" ::: "memory")

#define STAGE_A(bufc, half, tile) do { \
    const bf16* s0_ = pA + (size_t)(half) * 64 * 1024 + (tile) * 64; \
    bf16* d0_ = ldsA + (bufc) * 16384 + (half) * 8192; \
    gload_lds16(s0_, d0_); \
    gload_lds16(s0_ + (size_t)128 * 1024, d0_ + 4096); \
} while(0)

#define STAGE_B(bufc, half, tile) do { \
    const bf16* s0_ = pB + (size_t)(half) * 32 * 1024 + (tile) * 64; \
    bf16* d0_ = ldsB + (bufc) * 16384 + (half) * 8192; \
    gload_lds16(s0_, d0_); \
    gload_lds16(s0_ + (size_t)128 * 1024, d0_ + 4096); \
} while(0)

#define LDA(bufc, mh) do { \
    const bf16* p_ = sm + (bufc) * 16384 + (mh) * 8192; \
    _Pragma("unroll") \
    for (int j_ = 0; j_ < 4; ++j_) { \
        a[j_][0] = *(const u32x4*)(p_ + j_ * 1024 + eA0); \
        a[j_][1] = *(const u32x4*)(p_ + j_ * 1024 + eA1); \
    } \
} while(0)

#define LDB(bufc, nh) do { \
    const bf16* p_ = sm + 32768 + (bufc) * 16384 + (nh) * 8192; \
    _Pragma("unroll") \
    for (int j_ = 0; j_ < 2; ++j_) { \
        b[(nh)*2 + j_][0] = *(const u32x4*)(p_ + j_ * 1024 + eB0); \
        b[(nh)*2 + j_][1] = *(const u32x4*)(p_ + j_ * 1024 + eB1); \
    } \
} while(0)

#define MM(mh, nh) do { \
    _Pragma("unroll") \
    for (int j_ = 0; j_ < 4; ++j_) { \
        _Pragma("unroll") \
        for (int i_ = 0; i_ < 2; ++i_) { \
            f32x4 c_ = acc[(mh)*4 + j_][(nh)*2 + i_]; \
            c_ = mfma16(as_bf(a[j_][0]), as_bf(b[(nh)*2 + i_][0]), c_); \
            c_ = mfma16(as_bf(a[j_][1]), as_bf(b[(nh)*2 + i_][1]), c_); \
            acc[(mh)*4 + j_][(nh)*2 + i_] = c_; \
        } \
    } \
} while(0)

#define GEMM_MAINLOOP() \
    STAGE_A(0, 0, 0); STAGE_B(0, 0, 0); STAGE_B(0, 1, 0); STAGE_A(0, 1, 0); \
    STAGE_A(1, 0, 1); STAGE_B(1, 0, 1); STAGE_B(1, 1, 1); \
    asm volatile("s_waitcnt vmcnt(6)" ::: "memory"); \
    __builtin_amdgcn_s_barrier(); \
    _Pragma("unroll 1") \
    for (int t = 0; t < 8; ++t) { \
        const int T1 = 2 * t + 1; \
        const int n0 = (2 * t + 2 < 15) ? 2 * t + 2 : 15; \
        const int n1 = (2 * t + 3 < 15) ? 2 * t + 3 : 15; \
        LDA(0, 0); LDB(0, 0); STAGE_A(1, 1, T1); \
        PH_MID(); MM(0, 0); PH_END(); \
        LDB(0, 1); STAGE_A(0, 0, n0); \
        PH_MID(); MM(0, 1); PH_END(); \
        LDA(0, 1); STAGE_B(0, 0, n0); \
        PH_MID(); MM(1, 0); PH_END(); \
        STAGE_B(0, 1, n0); \
        PH_MID(); MM(1, 1); VM6(); PH_END(); \
        LDA(1, 0); LDB(1, 0); STAGE_A(0, 1, n0); \
        PH_MID(); MM(0, 0); PH_END(); \
        LDB(1, 1); STAGE_A(1, 0, n1); \
        PH_MID(); MM(0, 1); PH_END(); \
        LDA(1, 1); STAGE_B(1, 0, n1); \
        PH_MID(); MM(1, 0); PH_END(); \
        STAGE_B(1, 1, n1); \
        PH_MID(); MM(1, 1); VM6(); PH_END(); \
    } \
    asm volatile("s_waitcnt vmcnt(0)" ::: "memory")

// ======================= fused Q+KV projection GEMM =================
// blocks [0,176): Qb = Aq * Wq^T (44 x 4 tiles)
// blocks [176,944): Akv * Wkv^T (96 x 8 tiles); bn<4 -> Kb row-major,
//                   bn>=4 -> V written TRANSPOSED into Vt[(vb*16+h)][d][768].
__global__ __launch_bounds__(512) void gemm_qkv(
    const bf16* __restrict__ Aq, const bf16* __restrict__ Akv,
    const bf16* __restrict__ Wt,      // Wqkv_t [3072][1024]
    bf16* __restrict__ Qb, bf16* __restrict__ Kb, bf16* __restrict__ Vt)
{
    __shared__ bf16 sm[65536];
    const int tid = threadIdx.x, lane = tid & 63, wid = tid >> 6;

    int wg = blockIdx.x;
    {   // bijective XCD swizzle, nwg=944 (944%8==0 -> q=118, r=0)
        const int xcd = wg & 7, off = wg >> 3;
        wg = xcd * 118 + off;
    }
    const bool isQ = wg < 176;
    const bf16* A;  const bf16* Bt;  int bm, bn;
    if (isQ) { A = Aq;  Bt = Wt;                      bm = wg % 44;  bn = wg / 44; }
    else     { wg -= 176;
               A = Akv; Bt = Wt + (size_t)1024 * 1024; bm = wg % 96;  bn = wg / 96; }

    const int wr = wid >> 2, wc = wid & 3;
    const int l15 = lane & 15, l4 = lane >> 4;

    const int Rrow = (wid << 3) + (lane >> 3);
    const int G    = (lane & 7) ^ (lane >> 3);
    const bf16* pA = A  + (size_t)(bm * 256 + Rrow) * 1024 + G * 8;
    const int wc1 = Rrow >> 5, cc1 = Rrow & 31;
    const bf16* pB = Bt + (size_t)(bn * 256 + wc1 * 64 + cc1) * 1024 + G * 8;
    bf16* ldsA = sm + (wid << 9);
    bf16* ldsB = sm + 32768 + (wid << 9);

    const int g0  = l4 ^ (l15 & 7);
    const int eA0 = wr * 4096 + l15 * 64 + g0 * 8;
    const int eA1 = eA0 ^ 32;
    const int eB0 = wc * 2048 + l15 * 64 + g0 * 8;
    const int eB1 = eB0 ^ 32;

    f32x4 acc[8][4];
    u32x4 a[4][2], b[4][2];
    const f32x4 zf = {0.f, 0.f, 0.f, 0.f};
    #pragma unroll
    for (int m = 0; m < 8; ++m)
        #pragma unroll
        for (int n = 0; n < 4; ++n) acc[m][n] = zf;

    GEMM_MAINLOOP();

    if (isQ || bn < 4) {
        // row-major bf16 store, N=1024
        bf16* C = isQ ? Qb : Kb;
        #pragma unroll
        for (int m = 0; m < 8; ++m) {
            const int row = bm * 256 + wr * 128 + m * 16 + l4 * 4;
            #pragma unroll
            for (int n = 0; n < 4; ++n) {
                const int col = bn * 256 + wc * 64 + n * 16 + l15;
                f32x4 v = acc[m][n];
                #pragma unroll
                for (int r = 0; r < 4; ++r)
                    C[(size_t)(row + r) * 1024 + col] = (bf16)v[r];
            }
        }
    } else {
        // V transposed store: lane's 4 regs = 4 consecutive kv positions j at one d
        const int vb = bm / 3;                 // b*8+chunk (768 rows per group, 3 tiles)
        const int j0base = (bm % 3) * 256;
        #pragma unroll
        for (int m = 0; m < 8; ++m) {
            const int j0 = j0base + wr * 128 + m * 16 + l4 * 4;
            #pragma unroll
            for (int n = 0; n < 4; ++n) {
                const int colv = (bn - 4) * 256 + wc * 64 + n * 16 + l15; // h*64+d
                f32x4 v = acc[m][n];
                u16x4 pk;
                #pragma unroll
                for (int r = 0; r < 4; ++r) {
                    bf16 t = (bf16)v[r];
                    pk[r] = __builtin_bit_cast(unsigned short, t);
                }
                *(u16x4*)(Vt + ((size_t)vb * 1024 + colv) * KVL + j0) = pk;
            }
        }
    }
}

// ======================= out GEMM (unchanged 8-phase) ===============
__global__ __launch_bounds__(512) void gemm_out(
    const bf16* __restrict__ A, const bf16* __restrict__ Bt,
    float* __restrict__ Cf, const float* __restrict__ bias)
{
    __shared__ bf16 sm[65536];
    const int tid = threadIdx.x, lane = tid & 63, wid = tid >> 6;

    int wg = blockIdx.x;
    {   // nwg=176: q=22, r=0
        const int xcd = wg & 7, off = wg >> 3;
        wg = xcd * 22 + off;
    }
    const int bm = wg % 44, bn = wg / 44;
    const int wr = wid >> 2, wc = wid & 3;
    const int l15 = lane & 15, l4 = lane >> 4;

    const int Rrow = (wid << 3) + (lane >> 3);
    const int G    = (lane & 7) ^ (lane >> 3);
    const bf16* pA = A  + (size_t)(bm * 256 + Rrow) * 1024 + G * 8;
    const int wc1 = Rrow >> 5, cc1 = Rrow & 31;
    const bf16* pB = Bt + (size_t)(bn * 256 + wc1 * 64 + cc1) * 1024 + G * 8;
    bf16* ldsA = sm + (wid << 9);
    bf16* ldsB = sm + 32768 + (wid << 9);

    const int g0  = l4 ^ (l15 & 7);
    const int eA0 = wr * 4096 + l15 * 64 + g0 * 8;
    const int eA1 = eA0 ^ 32;
    const int eB0 = wc * 2048 + l15 * 64 + g0 * 8;
    const int eB1 = eB0 ^ 32;

    f32x4 acc[8][4];
    u32x4 a[4][2], b[4][2];
    const f32x4 zf = {0.f, 0.f, 0.f, 0.f};
    #pragma unroll
    for (int m = 0; m < 8; ++m)
        #pragma unroll
        for (int n = 0; n < 4; ++n) acc[m][n] = zf;

    GEMM_MAINLOOP();

    #pragma unroll
    for (int m = 0; m < 8; ++m) {
        const int row = bm * 256 + wr * 128 + m * 16 + l4 * 4;
        #pragma unroll
        for (int n = 0; n < 4; ++n) {
            const int col = bn * 256 + wc * 64 + n * 16 + l15;
            f32x4 v = acc[m][n];
            const float bs = bias[col];
            #pragma unroll
            for (int r = 0; r < 4; ++r)
                Cf[(size_t)(row + r) * 1024 + col] = v[r] + bs;
        }
    }
}

// ======================= flash attention (K stride 1024) ============
__global__ __launch_bounds__(256, 4) void attn_fwd(
    const bf16* __restrict__ Q, const bf16* __restrict__ K,
    const bf16* __restrict__ Vt, bf16* __restrict__ O)
{
    __shared__ bf16 Kl[2][2][64][32];
    __shared__ bf16 Vl[2][2][64][32];

    const int tid = threadIdx.x, lane = tid & 63, wid = tid >> 6;
    int bid = blockIdx.x;
    const int h = bid & 15; bid >>= 4;
    const int qt = bid % 44, b = bid / 44;
    const int chunk = qt < 28 ? (qt >> 2) : 7;
    const int qrow0 = b * (TOUT * S_) +
                      (qt < 28 ? chunk * S_ + (qt & 3) * 64 : 7 * S_ + (qt - 28) * 64);

    const bf16* kg = K  + ((size_t)(b * 8 + chunk) * KVL) * 1024 + h * 64;
    const bf16* vg = Vt + ((size_t)((b * 8 + chunk) * 16 + h)) * 64 * KVL;

    const int l15 = lane & 15, l4 = lane >> 4;

    const bf16* qp = Q + (size_t)(qrow0 + wid * 16 + l15) * D_ + h * 64 + l4 * 8;
    u32x4 q0, q1;
    {
        bf16x8 t0 = *(const bf16x8*)qp;
        bf16x8 t1 = *(const bf16x8*)(qp + 32);
        #pragma unroll
        for (int j = 0; j < 8; ++j) {
            t0[j] = (bf16)((float)t0[j] * 0.125f);
            t1[j] = (bf16)((float)t1[j] * 0.125f);
        }
        q0 = __builtin_bit_cast(u32x4, t0);
        q1 = __builtin_bit_cast(u32x4, t1);
    }

    const int R   = wid * 16 + (lane >> 2);
    const int gsw = ((lane & 3) ^ ((lane >> 3) & 3)) * 8;
    const int rg  = (l4 ^ ((l15 >> 1) & 3)) * 8;

    const int baseA = ((2 * (l4 & 1)) * 16 + l15) * 4;
    const int baseB = baseA + 64;
    const bool hi2 = (l4 & 2) != 0;

    float m_s = -1e30f, l_s = 0.f;
    f32x4 oacc[4];
    const f32x4 zf = {0.f, 0.f, 0.f, 0.f};
    #pragma unroll
    for (int m2 = 0; m2 < 4; ++m2) oacc[m2] = zf;

#define ASTAGE(c, t) do { \
    const int kv0_ = (t) * 64; \
    gload_lds16(kg + (size_t)(kv0_ + R) * 1024 + gsw,      &Kl[c][0][0][0] + wid * 512); \
    gload_lds16(kg + (size_t)(kv0_ + R) * 1024 + 32 + gsw, &Kl[c][1][0][0] + wid * 512); \
    gload_lds16(vg + (size_t)R * KVL + kv0_ + gsw,         &Vl[c][0][0][0] + wid * 512); \
    gload_lds16(vg + (size_t)R * KVL + kv0_ + 32 + gsw,    &Vl[c][1][0][0] + wid * 512); \
} while (0)

    ASTAGE(0, 0);
    __syncthreads();

    #pragma unroll 1
    for (int kt = 0; kt < 12; ++kt) {
        const int cur = kt & 1;
        if (kt < 11) ASTAGE(cur ^ 1, kt + 1);

        f32x4 s[4];
        #pragma unroll
        for (int n = 0; n < 4; ++n) {
            const bf16* kp = &Kl[cur][0][n * 16 + l15][0] + rg;
            const u32x4 k0 = *(const u32x4*)kp;
            const u32x4 k1 = *(const u32x4*)(kp + 2048);
            f32x4 t = mfma16(as_bf(k0), as_bf(q0), zf);
            s[n] = mfma16(as_bf(k1), as_bf(q1), t);
        }

        float pm = s[0][0];
        #pragma unroll
        for (int n = 0; n < 4; ++n)
            #pragma unroll
            for (int r = 0; r < 4; ++r) pm = fmaxf(pm, s[n][r]);
        pm = fmaxf(pm, __shfl_xor(pm, 16));
        pm = fmaxf(pm, __shfl_xor(pm, 32));
        const float mn = fmaxf(m_s, pm);
        const float al = __expf(m_s - mn);
        m_s = mn;
        float p[4][4];
        float sum = 0.f;
        #pragma unroll
        for (int n = 0; n < 4; ++n)
            #pragma unroll
            for (int r = 0; r < 4; ++r) {
                const float e = __expf(s[n][r] - mn);
                p[n][r] = e; sum += e;
            }
        sum += __shfl_xor(sum, 16);
        sum += __shfl_xor(sum, 32);
        l_s = l_s * al + sum;
        #pragma unroll
        for (int m2 = 0; m2 < 4; ++m2) oacc[m2] *= al;

        int u[4][2];
        #pragma unroll
        for (int n = 0; n < 4; ++n) {
            u[n][0] = cvtpk(p[n][0], p[n][1]);
            u[n][1] = cvtpk(p[n][2], p[n][3]);
        }

        #pragma unroll
        for (int kk = 0; kk < 2; ++kk) {
            const int e0 = __builtin_amdgcn_ds_bpermute(baseA, u[2 * kk][0]);
            const int f0 = __builtin_amdgcn_ds_bpermute(baseA, u[2 * kk + 1][0]);
            const int e1 = __builtin_amdgcn_ds_bpermute(baseA, u[2 * kk][1]);
            const int f1 = __builtin_amdgcn_ds_bpermute(baseA, u[2 * kk + 1][1]);
            const int e2 = __builtin_amdgcn_ds_bpermute(baseB, u[2 * kk][0]);
            const int f2 = __builtin_amdgcn_ds_bpermute(baseB, u[2 * kk + 1][0]);
            const int e3 = __builtin_amdgcn_ds_bpermute(baseB, u[2 * kk][1]);
            const int f3 = __builtin_amdgcn_ds_bpermute(baseB, u[2 * kk + 1][1]);
            u32x4 pb;
            pb[0] = (unsigned)(hi2 ? f0 : e0);
            pb[1] = (unsigned)(hi2 ? f1 : e1);
            pb[2] = (unsigned)(hi2 ? f2 : e2);
            pb[3] = (unsigned)(hi2 ? f3 : e3);
            #pragma unroll
            for (int m2 = 0; m2 < 4; ++m2) {
                const u32x4 vf = *(const u32x4*)(&Vl[cur][kk][m2 * 16 + l15][0] + rg);
                oacc[m2] = mfma16(as_bf(vf), as_bf(pb), oacc[m2]);
            }
        }
        __syncthreads();
    }
#undef ASTAGE

    const float inv = 1.f / l_s;
    bf16* sc = &Kl[0][0][0][0] + wid * 1152;
    #pragma unroll
    for (int m2 = 0; m2 < 4; ++m2)
        #pragma unroll
        for (int r = 0; r < 4; ++r)
            sc[l15 * 72 + m2 * 16 + l4 * 4 + r] = (bf16)(oacc[m2][r] * inv);
    const int rq = lane >> 2, rd = (lane & 3) * 16;
    const bf16* sr = sc + rq * 72 + rd;
    const u32x4 o0 = *(const u32x4*)sr;
    const u32x4 o1 = *(const u32x4*)(sr + 8);
    bf16* op = O + (size_t)(qrow0 + wid * 16 + rq) * D_ + h * 64 + rd;
    *(u32x4*)op = o0;
    *(u32x4*)(op + 8) = o1;
}

// ======================= launch =====================================
extern "C" void kernel_launch(void* const* d_in, const int* in_sizes, int n_in,
                              void* d_out, int out_size, void* d_ws, size_t ws_size,
                              hipStream_t stream) {
    (void)in_sizes; (void)n_in; (void)out_size; (void)ws_size;
    const float* x    = (const float*)d_in[0];
    const float* Wqkv = (const float*)d_in[1];
    const float* Wout = (const float*)d_in[2];
    const float* bout = (const float*)d_in[3];

    bf16* Aq     = (bf16*)d_ws;                       // 11264*1024
    bf16* Akv    = Aq     + (size_t)MQ  * 1024;       // 24576*1024
    bf16* Wqkv_t = Akv    + (size_t)MKV * 1024;       // 3072*1024
    bf16* Wout_t = Wqkv_t + (size_t)3072 * 1024;      // 1024*1024
    bf16* Qb     = Wout_t + (size_t)1024 * 1024;      // 11264*1024
    bf16* Kb     = Qb     + (size_t)MQ  * 1024;       // 24576*1024
    bf16* Vtb    = Kb     + (size_t)MKV * 1024;       // 24576*1024 (as 512x64x768)
    bf16* Ob     = Aq;    // alias: Aq dead after gemm_qkv

    prep<<<PB_TOT, 256, 0, stream>>>(x, Wqkv, Wout, Aq, Akv, Wqkv_t, Wout_t);

    gemm_qkv<<<944, 512, 0, stream>>>(Aq, Akv, Wqkv_t, Qb, Kb, Vtb);

    attn_fwd<<<4 * 44 * 16, 256, 0, stream>>>(Qb, Kb, Vtb, Ob);

    gemm_out<<<176, 512, 0, stream>>>(Ob, Wout_t, (float*)d_out, bout);
}

// Round 5
// 306.564 us; speedup vs baseline: 1.2082x; 1.0061x over previous
//
// MemFullAttention_19585050870313 — MI355X round 5
// Change vs round 4: GEMM phase schedule rebuilt as read-prefetch-balanced:
//   - exactly 6 ds_read_b128 per phase (was 12/4/8/0) -> LDS pipe 576 cyc/phase < MFMA 620
//   - reads issued one phase EARLY (post-MM), double-buffered regs aX/aY/bP/bQ
//   - vmcnt(6) at every phase end (global stage-landing guard, distance-4 proof)
// prep / attn_fwd unchanged from round 4.
#include <hip/hip_runtime.h>
#include <hip/hip_bf16.h>

typedef __bf16 bf16;
typedef __bf16 bf16x8 __attribute__((ext_vector_type(8)));
typedef float  f32x4  __attribute__((ext_vector_type(4)));
typedef float  f32x4v __attribute__((ext_vector_type(4)));
typedef unsigned int u32x4 __attribute__((ext_vector_type(4)));
typedef unsigned short u16x4 __attribute__((ext_vector_type(4)));

#define DEV __device__ __forceinline__

DEV void gload_lds16(const bf16* g, bf16* l) {
    __builtin_amdgcn_global_load_lds(
        (__attribute__((address_space(1))) void*)g,
        (__attribute__((address_space(3))) void*)l, 16, 0, 0);
}

DEV bf16x8 as_bf(u32x4 v) { return __builtin_bit_cast(bf16x8, v); }

DEV f32x4 mfma16(bf16x8 a, bf16x8 b, f32x4 c) {
    return __builtin_amdgcn_mfma_f32_16x16x32_bf16(a, b, c, 0, 0, 0);
}

DEV int cvtpk(float lo, float hi) {
    int r;
    asm("v_cvt_pk_bf16_f32 %0, %1, %2" : "=v"(r) : "v"(lo), "v"(hi));
    return r;
}

// ---- problem constants (reference_length fixed at 3) ----
constexpr int D_   = 1024;
constexpr int S_   = 256;
constexpr int TOUT = 11;
constexpr int MQ   = 4 * TOUT * S_;   // 11264
constexpr int MKV  = 4 * 8 * 3 * S_;  // 24576
constexpr int KVL  = 768;

constexpr int PB_WQKV = 768;
constexpr int PB_WOUT = 256;
constexpr int PB_GQ   = MQ  * 128 / 256;     // 5632
constexpr int PB_GKV  = MKV * 128 / 256;     // 12288
constexpr int PB_TOT  = PB_WQKV + PB_WOUT + PB_GQ + PB_GKV;

// ======================= fused prep (unchanged) =====================
__global__ void prep(const float* __restrict__ x,
                     const float* __restrict__ Wqkv,
                     const float* __restrict__ Wout,
                     bf16* __restrict__ Aq, bf16* __restrict__ Akv,
                     bf16* __restrict__ Wqkv_t, bf16* __restrict__ Wout_t)
{
    __shared__ float T[64][65];
    const int tid = threadIdx.x;
    int wg = blockIdx.x;

    if (wg < PB_WQKV + PB_WOUT) {
        const float* W; bf16* Wt; int N, bid2;
        if (wg < PB_WQKV) { W = Wqkv; Wt = Wqkv_t; N = 3072; bid2 = wg; }
        else              { W = Wout; Wt = Wout_t; N = 1024; bid2 = wg - PB_WQKV; }
        const int kt = bid2 & 15, nt = bid2 >> 4;
        const int k0 = kt * 64, n0 = nt * 64;
        for (int i = 0; i < 16; ++i) {
            const int e = i * 256 + tid;
            const int kk = e >> 6, nn = e & 63;
            T[nn][kk] = W[(size_t)(k0 + kk) * N + n0 + nn];
        }
        __syncthreads();
        for (int i = 0; i < 16; ++i) {
            const int e = i * 256 + tid;
            const int n = e >> 6, kk = e & 63;
            Wt[(size_t)(n0 + n) * 1024 + k0 + kk] = (bf16)T[n][kk];
        }
        return;
    }
    wg -= PB_WQKV + PB_WOUT;

    int row, part;
    const float* src;
    bf16* dst;
    if (wg < PB_GQ) {
        const int idx = wg * 256 + tid;
        row = idx >> 7; part = idx & 127;
        const int b    = row / (TOUT * S_);
        const int r2   = row - b * (TOUT * S_);
        const int tout = r2 >> 8;
        const int s    = r2 & 255;
        const int tx   = tout < 7 ? tout * 4 : 28 + (tout - 7);
        src = x + ((size_t)((b * 32 + tx) * S_ + s)) * D_ + part * 8;
        dst = Aq + (size_t)row * D_ + part * 8;
    } else {
        const int idx = (wg - PB_GQ) * 256 + tid;
        row = idx >> 7; part = idx & 127;
        const int b  = row / 6144;
        const int r2 = row - b * 6144;
        const int c  = r2 / KVL;
        const int j  = r2 - c * KVL;
        const int f  = 1 + (j >> 8);
        const int s  = j & 255;
        const int tx = c * 4 + f;
        src = x + ((size_t)((b * 32 + tx) * S_ + s)) * D_ + part * 8;
        dst = Akv + (size_t)row * D_ + part * 8;
    }
    f32x4v v0 = *(const f32x4v*)src;
    f32x4v v1 = *(const f32x4v*)(src + 4);
    bf16x8 o;
    o[0]=(bf16)v0[0]; o[1]=(bf16)v0[1]; o[2]=(bf16)v0[2]; o[3]=(bf16)v0[3];
    o[4]=(bf16)v1[0]; o[5]=(bf16)v1[1]; o[6]=(bf16)v1[2]; o[7]=(bf16)v1[3];
    *(bf16x8*)dst = o;
}

// ======================= 8-phase GEMM, balanced read-prefetch =======
#define PH_BEGIN() do { \
    __builtin_amdgcn_s_barrier(); \
    asm volatile("s_waitcnt lgkmcnt(0)" ::: "memory"); \
    __builtin_amdgcn_sched_barrier(0); \
    __builtin_amdgcn_s_setprio(1); \
} while(0)

#define PH_MMEND() do { \
    __builtin_amdgcn_s_setprio(0); \
    __builtin_amdgcn_sched_barrier(0); \
} while(0)

#define PH_CLOSE() do { \
    asm volatile("s_waitcnt vmcnt(6)" ::: "memory"); \
    __builtin_amdgcn_s_barrier(); \
} while(0)

#define STAGE_A(bufc, half, tile) do { \
    const bf16* s0_ = pA + (size_t)(half) * 64 * 1024 + (tile) * 64; \
    bf16* d0_ = ldsA + (bufc) * 16384 + (half) * 8192; \
    gload_lds16(s0_, d0_); \
    gload_lds16(s0_ + (size_t)128 * 1024, d0_ + 4096); \
} while(0)

#define STAGE_B(bufc, half, tile) do { \
    const bf16* s0_ = pB + (size_t)(half) * 32 * 1024 + (tile) * 64; \
    bf16* d0_ = ldsB + (bufc) * 16384 + (half) * 8192; \
    gload_lds16(s0_, d0_); \
    gload_lds16(s0_ + (size_t)128 * 1024, d0_ + 4096); \
} while(0)

// 2 ds_read_b128: one A j-frag (both k-slices)
#define LDAJ(dst, bufc, mh, J) do { \
    const bf16* p_ = sm + (bufc) * 16384 + (mh) * 8192 + (J) * 1024; \
    dst[J][0] = *(const u32x4*)(p_ + eA0); \
    dst[J][1] = *(const u32x4*)(p_ + eA1); \
} while(0)

// 4 ds_read_b128: both B i-frags of one half
#define LDBH(dst, bufc, nh) do { \
    const bf16* p_ = sm + 32768 + (bufc) * 16384 + (nh) * 8192; \
    dst[0][0] = *(const u32x4*)(p_ + eB0); \
    dst[0][1] = *(const u32x4*)(p_ + eB1); \
    dst[1][0] = *(const u32x4*)(p_ + 1024 + eB0); \
    dst[1][1] = *(const u32x4*)(p_ + 1024 + eB1); \
} while(0)

#define MMX(av, bv, mh, nh) do { \
    _Pragma("unroll") \
    for (int j_ = 0; j_ < 4; ++j_) { \
        _Pragma("unroll") \
        for (int i_ = 0; i_ < 2; ++i_) { \
            f32x4 c_ = acc[(mh)*4 + j_][(nh)*2 + i_]; \
            c_ = mfma16(as_bf(av[j_][0]), as_bf(bv[i_][0]), c_); \
            c_ = mfma16(as_bf(av[j_][1]), as_bf(bv[i_][1]), c_); \
            acc[(mh)*4 + j_][(nh)*2 + i_] = c_; \
        } \
    } \
} while(0)

// Schedule (per iter t: buf0=tile 2t, buf1=2t+1; stages n0=2t+2, n1=2t+3):
//  ph1 stage A1h1(2t+1) | MM(aX,bP,0,0) | read bQ(0,1)+aY(0,1,j0)
//  ph2 stage A0h0(n0)   | MM(aX,bQ,0,1) | read aY(0,1,j1..3)
//  ph3 stage B0h0(n0)   | MM(aY,bP,1,0) | read aX(1,0,j0..2)
//  ph4 stage B0h1(n0)   | MM(aY,bQ,1,1) | read aX(1,0,j3)+bP(1,0)
//  ph5 stage A0h1(n0)   | MM(aX,bP,0,0) | read bQ(1,1)+aY(1,1,j0)
//  ph6 stage A1h0(n1)   | MM(aX,bQ,0,1) | read aY(1,1,j1..3)
//  ph7 stage B1h0(n1)   | MM(aY,bP,1,0) | read aX(0,0,j0..2)'
//  ph8 stage B1h1(n1)   | MM(aY,bQ,1,1) | read aX(0,0,j3)'+bP(0,0)'
// Every read's stage-distance >= 4 (guarded by per-phase vmcnt(6)+barrier);
// every stage's slot had its last reg-read >= 2 phases earlier.
#define GEMM_MAINLOOP() do { \
    STAGE_A(0, 0, 0); STAGE_A(0, 1, 0); STAGE_B(0, 0, 0); STAGE_B(0, 1, 0); \
    STAGE_A(1, 0, 1); STAGE_B(1, 0, 1); STAGE_B(1, 1, 1); \
    asm volatile("s_waitcnt vmcnt(6)" ::: "memory"); \
    __builtin_amdgcn_s_barrier(); \
    LDAJ(aX,0,0,0); LDAJ(aX,0,0,1); LDAJ(aX,0,0,2); LDAJ(aX,0,0,3); \
    LDBH(bP,0,0); \
    _Pragma("unroll 1") \
    for (int t = 0; t < 8; ++t) { \
        const int T1 = 2 * t + 1; \
        const int n0 = (2 * t + 2 < 15) ? 2 * t + 2 : 15; \
        const int n1 = (2 * t + 3 < 15) ? 2 * t + 3 : 15; \
        STAGE_A(1, 1, T1); \
        PH_BEGIN(); MMX(aX, bP, 0, 0); PH_MMEND(); \
        LDBH(bQ, 0, 1); LDAJ(aY, 0, 1, 0); \
        PH_CLOSE(); \
        STAGE_A(0, 0, n0); \
        PH_BEGIN(); MMX(aX, bQ, 0, 1); PH_MMEND(); \
        LDAJ(aY, 0, 1, 1); LDAJ(aY, 0, 1, 2); LDAJ(aY, 0, 1, 3); \
        PH_CLOSE(); \
        STAGE_B(0, 0, n0); \
        PH_BEGIN(); MMX(aY, bP, 1, 0); PH_MMEND(); \
        LDAJ(aX, 1, 0, 0); LDAJ(aX, 1, 0, 1); LDAJ(aX, 1, 0, 2); \
        PH_CLOSE(); \
        STAGE_B(0, 1, n0); \
        PH_BEGIN(); MMX(aY, bQ, 1, 1); PH_MMEND(); \
        LDAJ(aX, 1, 0, 3); LDBH(bP, 1, 0); \
        PH_CLOSE(); \
        STAGE_A(0, 1, n0); \
        PH_BEGIN(); MMX(aX, bP, 0, 0); PH_MMEND(); \
        LDBH(bQ, 1, 1); LDAJ(aY, 1, 1, 0); \
        PH_CLOSE(); \
        STAGE_A(1, 0, n1); \
        PH_BEGIN(); MMX(aX, bQ, 0, 1); PH_MMEND(); \
        LDAJ(aY, 1, 1, 1); LDAJ(aY, 1, 1, 2); LDAJ(aY, 1, 1, 3); \
        PH_CLOSE(); \
        STAGE_B(1, 0, n1); \
        PH_BEGIN(); MMX(aY, bP, 1, 0); PH_MMEND(); \
        LDAJ(aX, 0, 0, 0); LDAJ(aX, 0, 0, 1); LDAJ(aX, 0, 0, 2); \
        PH_CLOSE(); \
        STAGE_B(1, 1, n1); \
        PH_BEGIN(); MMX(aY, bQ, 1, 1); PH_MMEND(); \
        LDAJ(aX, 0, 0, 3); LDBH(bP, 0, 0); \
        PH_CLOSE(); \
    } \
    asm volatile("s_waitcnt vmcnt(0) lgkmcnt(0)" ::: "memory"); \
} while(0)

#define GEMM_PREAMBLE() \
    const int wr = wid >> 2, wc = wid & 3; \
    const int l15 = lane & 15, l4 = lane >> 4; \
    const int Rrow = (wid << 3) + (lane >> 3); \
    const int G    = (lane & 7) ^ (lane >> 3); \
    const bf16* pA = A  + (size_t)(bm * 256 + Rrow) * 1024 + G * 8; \
    const int wc1 = Rrow >> 5, cc1 = Rrow & 31; \
    const bf16* pB = Bt + (size_t)(bn * 256 + wc1 * 64 + cc1) * 1024 + G * 8; \
    bf16* ldsA = sm + (wid << 9); \
    bf16* ldsB = sm + 32768 + (wid << 9); \
    const int g0  = l4 ^ (l15 & 7); \
    const int eA0 = wr * 4096 + l15 * 64 + g0 * 8; \
    const int eA1 = eA0 ^ 32; \
    const int eB0 = wc * 2048 + l15 * 64 + g0 * 8; \
    const int eB1 = eB0 ^ 32; \
    f32x4 acc[8][4]; \
    u32x4 aX[4][2], aY[4][2], bP[2][2], bQ[2][2]; \
    { const f32x4 zf_ = {0.f, 0.f, 0.f, 0.f}; \
      _Pragma("unroll") \
      for (int m_ = 0; m_ < 8; ++m_) \
          _Pragma("unroll") \
          for (int n_ = 0; n_ < 4; ++n_) acc[m_][n_] = zf_; }

// ======================= fused Q+KV projection GEMM =================
__global__ __launch_bounds__(512, 2) void gemm_qkv(
    const bf16* __restrict__ Aq, const bf16* __restrict__ Akv,
    const bf16* __restrict__ Wt,
    bf16* __restrict__ Qb, bf16* __restrict__ Kb, bf16* __restrict__ Vt)
{
    __shared__ bf16 sm[65536];
    const int tid = threadIdx.x, lane = tid & 63, wid = tid >> 6;

    int wg = blockIdx.x;
    {   // bijective XCD swizzle, nwg=944
        const int xcd = wg & 7, off = wg >> 3;
        wg = xcd * 118 + off;
    }
    const bool isQ = wg < 176;
    const bf16* A;  const bf16* Bt;  int bm, bn;
    if (isQ) { A = Aq;  Bt = Wt;                       bm = wg % 44;  bn = wg / 44; }
    else     { wg -= 176;
               A = Akv; Bt = Wt + (size_t)1024 * 1024; bm = wg % 96;  bn = wg / 96; }

    GEMM_PREAMBLE();
    GEMM_MAINLOOP();

    if (isQ || bn < 4) {
        bf16* C = isQ ? Qb : Kb;
        #pragma unroll
        for (int m = 0; m < 8; ++m) {
            const int row = bm * 256 + wr * 128 + m * 16 + l4 * 4;
            #pragma unroll
            for (int n = 0; n < 4; ++n) {
                const int col = bn * 256 + wc * 64 + n * 16 + l15;
                f32x4 v = acc[m][n];
                #pragma unroll
                for (int r = 0; r < 4; ++r)
                    C[(size_t)(row + r) * 1024 + col] = (bf16)v[r];
            }
        }
    } else {
        const int vb = bm / 3;
        const int j0base = (bm % 3) * 256;
        #pragma unroll
        for (int m = 0; m < 8; ++m) {
            const int j0 = j0base + wr * 128 + m * 16 + l4 * 4;
            #pragma unroll
            for (int n = 0; n < 4; ++n) {
                const int colv = (bn - 4) * 256 + wc * 64 + n * 16 + l15;
                f32x4 v = acc[m][n];
                u16x4 pk;
                #pragma unroll
                for (int r = 0; r < 4; ++r) {
                    bf16 t = (bf16)v[r];
                    pk[r] = __builtin_bit_cast(unsigned short, t);
                }
                *(u16x4*)(Vt + ((size_t)vb * 1024 + colv) * KVL + j0) = pk;
            }
        }
    }
}

// ======================= out GEMM ===================================
__global__ __launch_bounds__(512, 2) void gemm_out(
    const bf16* __restrict__ A, const bf16* __restrict__ Bt,
    float* __restrict__ Cf, const float* __restrict__ bias)
{
    __shared__ bf16 sm[65536];
    const int tid = threadIdx.x, lane = tid & 63, wid = tid >> 6;

    int wg = blockIdx.x;
    {   // nwg=176: q=22
        const int xcd = wg & 7, off = wg >> 3;
        wg = xcd * 22 + off;
    }
    const int bm = wg % 44, bn = wg / 44;

    GEMM_PREAMBLE();
    GEMM_MAINLOOP();

    #pragma unroll
    for (int m = 0; m < 8; ++m) {
        const int row = bm * 256 + wr * 128 + m * 16 + l4 * 4;
        #pragma unroll
        for (int n = 0; n < 4; ++n) {
            const int col = bn * 256 + wc * 64 + n * 16 + l15;
            f32x4 v = acc[m][n];
            const float bs = bias[col];
            #pragma unroll
            for (int r = 0; r < 4; ++r)
                Cf[(size_t)(row + r) * 1024 + col] = v[r] + bs;
        }
    }
}

// ======================= flash attention (unchanged) ================
__global__ __launch_bounds__(256, 4) void attn_fwd(
    const bf16* __restrict__ Q, const bf16* __restrict__ K,
    const bf16* __restrict__ Vt, bf16* __restrict__ O)
{
    __shared__ bf16 Kl[2][2][64][32];
    __shared__ bf16 Vl[2][2][64][32];

    const int tid = threadIdx.x, lane = tid & 63, wid = tid >> 6;
    int bid = blockIdx.x;
    const int h = bid & 15; bid >>= 4;
    const int qt = bid % 44, b = bid / 44;
    const int chunk = qt < 28 ? (qt >> 2) : 7;
    const int qrow0 = b * (TOUT * S_) +
                      (qt < 28 ? chunk * S_ + (qt & 3) * 64 : 7 * S_ + (qt - 28) * 64);

    const bf16* kg = K  + ((size_t)(b * 8 + chunk) * KVL) * 1024 + h * 64;
    const bf16* vg = Vt + ((size_t)((b * 8 + chunk) * 16 + h)) * 64 * KVL;

    const int l15 = lane & 15, l4 = lane >> 4;

    const bf16* qp = Q + (size_t)(qrow0 + wid * 16 + l15) * D_ + h * 64 + l4 * 8;
    u32x4 q0, q1;
    {
        bf16x8 t0 = *(const bf16x8*)qp;
        bf16x8 t1 = *(const bf16x8*)(qp + 32);
        #pragma unroll
        for (int j = 0; j < 8; ++j) {
            t0[j] = (bf16)((float)t0[j] * 0.125f);
            t1[j] = (bf16)((float)t1[j] * 0.125f);
        }
        q0 = __builtin_bit_cast(u32x4, t0);
        q1 = __builtin_bit_cast(u32x4, t1);
    }

    const int R   = wid * 16 + (lane >> 2);
    const int gsw = ((lane & 3) ^ ((lane >> 3) & 3)) * 8;
    const int rg  = (l4 ^ ((l15 >> 1) & 3)) * 8;

    const int baseA = ((2 * (l4 & 1)) * 16 + l15) * 4;
    const int baseB = baseA + 64;
    const bool hi2 = (l4 & 2) != 0;

    float m_s = -1e30f, l_s = 0.f;
    f32x4 oacc[4];
    const f32x4 zf = {0.f, 0.f, 0.f, 0.f};
    #pragma unroll
    for (int m2 = 0; m2 < 4; ++m2) oacc[m2] = zf;

#define ASTAGE(c, t) do { \
    const int kv0_ = (t) * 64; \
    gload_lds16(kg + (size_t)(kv0_ + R) * 1024 + gsw,      &Kl[c][0][0][0] + wid * 512); \
    gload_lds16(kg + (size_t)(kv0_ + R) * 1024 + 32 + gsw, &Kl[c][1][0][0] + wid * 512); \
    gload_lds16(vg + (size_t)R * KVL + kv0_ + gsw,         &Vl[c][0][0][0] + wid * 512); \
    gload_lds16(vg + (size_t)R * KVL + kv0_ + 32 + gsw,    &Vl[c][1][0][0] + wid * 512); \
} while (0)

    ASTAGE(0, 0);
    __syncthreads();

    #pragma unroll 1
    for (int kt = 0; kt < 12; ++kt) {
        const int cur = kt & 1;
        if (kt < 11) ASTAGE(cur ^ 1, kt + 1);

        f32x4 s[4];
        #pragma unroll
        for (int n = 0; n < 4; ++n) {
            const bf16* kp = &Kl[cur][0][n * 16 + l15][0] + rg;
            const u32x4 k0 = *(const u32x4*)kp;
            const u32x4 k1 = *(const u32x4*)(kp + 2048);
            f32x4 t = mfma16(as_bf(k0), as_bf(q0), zf);
            s[n] = mfma16(as_bf(k1), as_bf(q1), t);
        }

        float pm = s[0][0];
        #pragma unroll
        for (int n = 0; n < 4; ++n)
            #pragma unroll
            for (int r = 0; r < 4; ++r) pm = fmaxf(pm, s[n][r]);
        pm = fmaxf(pm, __shfl_xor(pm, 16));
        pm = fmaxf(pm, __shfl_xor(pm, 32));
        const float mn = fmaxf(m_s, pm);
        const float al = __expf(m_s - mn);
        m_s = mn;
        float p[4][4];
        float sum = 0.f;
        #pragma unroll
        for (int n = 0; n < 4; ++n)
            #pragma unroll
            for (int r = 0; r < 4; ++r) {
                const float e = __expf(s[n][r] - mn);
                p[n][r] = e; sum += e;
            }
        sum += __shfl_xor(sum, 16);
        sum += __shfl_xor(sum, 32);
        l_s = l_s * al + sum;
        #pragma unroll
        for (int m2 = 0; m2 < 4; ++m2) oacc[m2] *= al;

        int u[4][2];
        #pragma unroll
        for (int n = 0; n < 4; ++n) {
            u[n][0] = cvtpk(p[n][0], p[n][1]);
            u[n][1] = cvtpk(p[n][2], p[n][3]);
        }

        #pragma unroll
        for (int kk = 0; kk < 2; ++kk) {
            const int e0 = __builtin_amdgcn_ds_bpermute(baseA, u[2 * kk][0]);
            const int f0 = __builtin_amdgcn_ds_bpermute(baseA, u[2 * kk + 1][0]);
            const int e1 = __builtin_amdgcn_ds_bpermute(baseA, u[2 * kk][1]);
            const int f1 = __builtin_amdgcn_ds_bpermute(baseA, u[2 * kk + 1][1]);
            const int e2 = __builtin_amdgcn_ds_bpermute(baseB, u[2 * kk][0]);
            const int f2 = __builtin_amdgcn_ds_bpermute(baseB, u[2 * kk + 1][0]);
            const int e3 = __builtin_amdgcn_ds_bpermute(baseB, u[2 * kk][1]);
            const int f3 = __builtin_amdgcn_ds_bpermute(baseB, u[2 * kk + 1][1]);
            u32x4 pb;
            pb[0] = (unsigned)(hi2 ? f0 : e0);
            pb[1] = (unsigned)(hi2 ? f1 : e1);
            pb[2] = (unsigned)(hi2 ? f2 : e2);
            pb[3] = (unsigned)(hi2 ? f3 : e3);
            #pragma unroll
            for (int m2 = 0; m2 < 4; ++m2) {
                const u32x4 vf = *(const u32x4*)(&Vl[cur][kk][m2 * 16 + l15][0] + rg);
                oacc[m2] = mfma16(as_bf(vf), as_bf(pb), oacc[m2]);
            }
        }
        __syncthreads();
    }
#undef ASTAGE

    const float inv = 1.f / l_s;
    bf16* sc = &Kl[0][0][0][0] + wid * 1152;
    #pragma unroll
    for (int m2 = 0; m2 < 4; ++m2)
        #pragma unroll
        for (int r = 0; r < 4; ++r)
            sc[l15 * 72 + m2 * 16 + l4 * 4 + r] = (bf16)(oacc[m2][r] * inv);
    const int rq = lane >> 2, rd = (lane & 3) * 16;
    const bf16* sr = sc + rq * 72 + rd;
    const u32x4 o0 = *(const u32x4*)sr;
    const u32x4 o1 = *(const u32x4*)(sr + 8);
    bf16* op = O + (size_t)(qrow0 + wid * 16 + rq) * D_ + h * 64 + rd;
    *(u32x4*)op = o0;
    *(u32x4*)(op + 8) = o1;
}

// ======================= launch =====================================
extern "C" void kernel_launch(void* const* d_in, const int* in_sizes, int n_in,
                              void* d_out, int out_size, void* d_ws, size_t ws_size,
                              hipStream_t stream) {
    (void)in_sizes; (void)n_in; (void)out_size; (void)ws_size;
    const float* x    = (const float*)d_in[0];
    const float* Wqkv = (const float*)d_in[1];
    const float* Wout = (const float*)d_in[2];
    const float* bout = (const float*)d_in[3];

    bf16* Aq     = (bf16*)d_ws;
    bf16* Akv    = Aq     + (size_t)MQ  * 1024;
    bf16* Wqkv_t = Akv    + (size_t)MKV * 1024;
    bf16* Wout_t = Wqkv_t + (size_t)3072 * 1024;
    bf16* Qb     = Wout_t + (size_t)1024 * 1024;
    bf16* Kb     = Qb     + (size_t)MQ  * 1024;
    bf16* Vtb    = Kb     + (size_t)MKV * 1024;
    bf16* Ob     = Aq;

    prep<<<PB_TOT, 256, 0, stream>>>(x, Wqkv, Wout, Aq, Akv, Wqkv_t, Wout_t);

    gemm_qkv<<<944, 512, 0, stream>>>(Aq, Akv, Wqkv_t, Qb, Kb, Vtb);

    attn_fwd<<<4 * 44 * 16, 256, 0, stream>>>(Qb, Kb, Vtb, Ob);

    gemm_out<<<176, 512, 0, stream>>>(Ob, Wout_t, (float*)d_out, bout);
}